// Round 6
// baseline (286.488 us; speedup 1.0000x reference)
//
#include <hip/hip_runtime.h>

#define D 1024
#define NH 16
#define HD 64
#define SEQ 2048
#define BATCH 4
#define LN_EPS 1e-5f
#define LOG2E 1.44269504088896f

typedef __attribute__((ext_vector_type(8))) __bf16 bf16x8;
typedef __attribute__((ext_vector_type(4))) float f32x4;

__device__ __forceinline__ ushort f2bf(float f) {
    union { float f; uint u; } c; c.f = f;
    uint u = c.u + 0x7fffu + ((c.u >> 16) & 1u);   // RNE
    return (ushort)(u >> 16);
}

// async global->LDS DMA, 16B per lane; LDS dest = wave-uniform base + lane*16
__device__ __forceinline__ void gl_lds16(const ushort* g, ushort* lds) {
    __builtin_amdgcn_global_load_lds(
        (const __attribute__((address_space(1))) void*)g,
        (__attribute__((address_space(3))) void*)lds, 16, 0, 0);
}

// raw v_exp_f32: D = 2^S0 (cdna4_isa §3). Single VALU inst, no OCML path.
__device__ __forceinline__ float exp2_raw(float v) {
    float e;
    asm("v_exp_f32 %0, %1" : "=v"(e) : "v"(v));
    return e;
}

// ---------------------------------------------------------------------------
// prep: fused {LayerNorm rows} + {fp32->bf16 convert of 4 weight matrices}.
// Blocks [0, 8192)      : LN, one row each (256 thr x float4), writes bf16.
// Blocks [8192, 12288)  : weight convert, 1024 floats per block.
// ---------------------------------------------------------------------------
__global__ __launch_bounds__(256) void prep(
    const float* __restrict__ x, const float* __restrict__ gamma,
    const float* __restrict__ beta, ushort* __restrict__ xn,
    const float* __restrict__ w0, const float* __restrict__ w1,
    const float* __restrict__ w2, const float* __restrict__ w3,
    ushort* __restrict__ wout)
{
    const int bid = blockIdx.x;
    const int tid = threadIdx.x;
    if (bid < BATCH * SEQ) {
        // ---- LayerNorm ----
        int row = bid;
        float4 v = ((const float4*)(x + (size_t)row * D))[tid];
        float s = v.x + v.y + v.z + v.w;
#pragma unroll
        for (int off = 32; off > 0; off >>= 1) s += __shfl_down(s, off, 64);
        __shared__ float red1[4], red2[4];
        int wid = tid >> 6, lane = tid & 63;
        if (lane == 0) red1[wid] = s;
        __syncthreads();
        float mean = (red1[0] + red1[1] + red1[2] + red1[3]) * (1.0f / D);
        float dx = v.x - mean, dy = v.y - mean, dz = v.z - mean, dw = v.w - mean;
        float ss = dx * dx + dy * dy + dz * dz + dw * dw;
#pragma unroll
        for (int off = 32; off > 0; off >>= 1) ss += __shfl_down(ss, off, 64);
        if (lane == 0) red2[wid] = ss;
        __syncthreads();
        float var = (red2[0] + red2[1] + red2[2] + red2[3]) * (1.0f / D);
        float rstd = rsqrtf(var + LN_EPS);
        float4 g = ((const float4*)gamma)[tid];
        float4 b = ((const float4*)beta)[tid];
        ushort4 o;
        o.x = f2bf(dx * rstd * g.x + b.x);
        o.y = f2bf(dy * rstd * g.y + b.y);
        o.z = f2bf(dz * rstd * g.z + b.z);
        o.w = f2bf(dw * rstd * g.w + b.w);
        ((ushort4*)(xn + (size_t)row * D))[tid] = o;
    } else {
        // ---- weight convert ----
        const int n = D * D;
        int p = bid - BATCH * SEQ;
        int sel = p >> 10;                 // 0..3
        int xblk = p & 1023;
        const float* in = sel == 0 ? w0 : (sel == 1 ? w1 : (sel == 2 ? w2 : w3));
        int i = (xblk * 256 + tid) * 4;
        float4 v = *(const float4*)(in + i);
        ushort4 o;
        o.x = f2bf(v.x); o.y = f2bf(v.y); o.z = f2bf(v.z); o.w = f2bf(v.w);
        *(ushort4*)(wout + (size_t)sel * n + i) = o;
    }
}

// ---------------------------------------------------------------------------
// Shared GEMM K-loop pieces: 128x128 tile, BK=64, XOR-swizzled DMA staging.
// 2-phase double-buffer: stage tile k+1 before computing tile k, single
// vmcnt-drain barrier per K-step. (Verified: 88.7-89.4 us, MfmaUtil 23.5.)
// ---------------------------------------------------------------------------
#define BM 128
#define BKK 64

// ---------------------------------------------------------------------------
// Fused QKV GEMM: W = stacked [Wq;Wk;Wv] = [3072][1024] bf16. Grid (24, 64).
// Region 0->Q, 1->K row-major bf16; region 2 -> V transposed to [B,H,D,S].
// ---------------------------------------------------------------------------
__global__ __launch_bounds__(256) void gemm_qkv(
    const ushort* __restrict__ A,    // [M,1024] bf16
    const ushort* __restrict__ W,    // [3072,1024] bf16
    const float* __restrict__ bq, const float* __restrict__ bk,
    const float* __restrict__ bv,
    ushort* __restrict__ Cq, ushort* __restrict__ Ck,
    ushort* __restrict__ CvT,
    int M, int K)
{
    __shared__ ushort As[2][BM * BKK];   // 2 x 16 KB
    __shared__ ushort Ws[2][BM * BKK];
    const int tid = threadIdx.x;
    const int lane = tid & 63;
    const int wave = tid >> 6;
    const int wr = wave >> 1, wc = wave & 1;
    const int m0 = blockIdx.y * BM;
    const int n0g = blockIdx.x * BM;
    const int region = n0g >> 10;
    const int n0l = n0g & 1023;
    const float* bias = region == 0 ? bq : (region == 1 ? bk : bv);
    const int fr = lane & 15, quad = lane >> 4;
    const int r8 = lane >> 3, c8 = lane & 7;
    const int gc8 = c8 ^ r8;               // swizzled global chunk
    const int swf = fr & 7;

    const ushort* gA = A + (size_t)(m0 + wave * 32 + r8) * K + gc8 * 8;
    const ushort* gW = W + (size_t)(n0g + wave * 32 + r8) * K + gc8 * 8;
    const int ldso = (wave * 32) * BKK;

    f32x4 acc[4][4] = {};

    // prologue: stage tile 0 into buffer 0
#pragma unroll
    for (int t = 0; t < 4; ++t) {
        gl_lds16(gA + (size_t)t * 8 * K, &As[0][ldso + t * 8 * BKK]);
        gl_lds16(gW + (size_t)t * 8 * K, &Ws[0][ldso + t * 8 * BKK]);
    }
    __syncthreads();

    for (int k0 = 0; k0 < K; k0 += BKK) {
        const int cur = (k0 >> 6) & 1;
        if (k0 + BKK < K) {
            const int nxt = cur ^ 1;
#pragma unroll
            for (int t = 0; t < 4; ++t) {
                gl_lds16(gA + (size_t)t * 8 * K + k0 + BKK, &As[nxt][ldso + t * 8 * BKK]);
                gl_lds16(gW + (size_t)t * 8 * K + k0 + BKK, &Ws[nxt][ldso + t * 8 * BKK]);
            }
        }
#pragma unroll
        for (int kh = 0; kh < 2; ++kh) {
            bf16x8 af[4], bf[4];
            const int co = ((kh * 4 + quad) ^ swf) * 8;
#pragma unroll
            for (int i = 0; i < 4; ++i) {
                af[i] = *(const bf16x8*)&As[cur][(wr * 64 + i * 16 + fr) * BKK + co];
                bf[i] = *(const bf16x8*)&Ws[cur][(wc * 64 + i * 16 + fr) * BKK + co];
            }
#pragma unroll
            for (int i = 0; i < 4; ++i)
#pragma unroll
                for (int j = 0; j < 4; ++j)
                    acc[i][j] = __builtin_amdgcn_mfma_f32_16x16x32_bf16(af[i], bf[j], acc[i][j], 0, 0, 0);
        }
        __syncthreads();   // drains prefetch vmcnt + fragment lgkm; one barrier/K-step
    }

#pragma unroll
    for (int j = 0; j < 4; ++j) {
        int col = n0l + wc * 64 + j * 16 + fr;
        float bvl = bias[col];
#pragma unroll
        for (int i = 0; i < 4; ++i) {
#pragma unroll
            for (int r = 0; r < 4; ++r) {
                int row = m0 + wr * 64 + i * 16 + quad * 4 + r;
                ushort hv = f2bf(acc[i][j][r] + bvl);
                if (region == 0) {
                    Cq[(size_t)row * 1024 + col] = hv;
                } else if (region == 1) {
                    Ck[(size_t)row * 1024 + col] = hv;
                } else {
                    int bb = row >> 11, s = row & 2047;
                    int hh = col >> 6, d = col & 63;
                    CvT[(((size_t)bb * NH + hh) * HD + d) * SEQ + s] = hv;
                }
            }
        }
    }
}

// ---------------------------------------------------------------------------
// Output projection GEMM (+bias +fp32 residual), same BK=64 dbuf structure.
// ---------------------------------------------------------------------------
__global__ __launch_bounds__(256) void gemm_out(
    const ushort* __restrict__ A, const ushort* __restrict__ W,
    const float* __restrict__ bias, const float* __restrict__ resid,
    float* __restrict__ Cf, int M, int N, int K)
{
    __shared__ ushort As[2][BM * BKK];
    __shared__ ushort Ws[2][BM * BKK];
    const int tid = threadIdx.x;
    const int lane = tid & 63;
    const int wave = tid >> 6;
    const int wr = wave >> 1, wc = wave & 1;
    const int m0 = blockIdx.y * BM, n0 = blockIdx.x * BM;
    const int fr = lane & 15, quad = lane >> 4;
    const int r8 = lane >> 3, c8 = lane & 7;
    const int gc8 = c8 ^ r8;
    const int swf = fr & 7;

    const ushort* gA = A + (size_t)(m0 + wave * 32 + r8) * K + gc8 * 8;
    const ushort* gW = W + (size_t)(n0 + wave * 32 + r8) * K + gc8 * 8;
    const int ldso = (wave * 32) * BKK;

    f32x4 acc[4][4] = {};

    // prologue: stage tile 0 into buffer 0
#pragma unroll
    for (int t = 0; t < 4; ++t) {
        gl_lds16(gA + (size_t)t * 8 * K, &As[0][ldso + t * 8 * BKK]);
        gl_lds16(gW + (size_t)t * 8 * K, &Ws[0][ldso + t * 8 * BKK]);
    }
    __syncthreads();

    for (int k0 = 0; k0 < K; k0 += BKK) {
        const int cur = (k0 >> 6) & 1;
        if (k0 + BKK < K) {
            const int nxt = cur ^ 1;
#pragma unroll
            for (int t = 0; t < 4; ++t) {
                gl_lds16(gA + (size_t)t * 8 * K + k0 + BKK, &As[nxt][ldso + t * 8 * BKK]);
                gl_lds16(gW + (size_t)t * 8 * K + k0 + BKK, &Ws[nxt][ldso + t * 8 * BKK]);
            }
        }
#pragma unroll
        for (int kh = 0; kh < 2; ++kh) {
            bf16x8 af[4], bf[4];
            const int co = ((kh * 4 + quad) ^ swf) * 8;
#pragma unroll
            for (int i = 0; i < 4; ++i) {
                af[i] = *(const bf16x8*)&As[cur][(wr * 64 + i * 16 + fr) * BKK + co];
                bf[i] = *(const bf16x8*)&Ws[cur][(wc * 64 + i * 16 + fr) * BKK + co];
            }
#pragma unroll
            for (int i = 0; i < 4; ++i)
#pragma unroll
                for (int j = 0; j < 4; ++j)
                    acc[i][j] = __builtin_amdgcn_mfma_f32_16x16x32_bf16(af[i], bf[j], acc[i][j], 0, 0, 0);
        }
        __syncthreads();
    }

#pragma unroll
    for (int j = 0; j < 4; ++j) {
        int col = n0 + wc * 64 + j * 16 + fr;
        float bvl = bias[col];
#pragma unroll
        for (int i = 0; i < 4; ++i) {
#pragma unroll
            for (int r = 0; r < 4; ++r) {
                int row = m0 + wr * 64 + i * 16 + quad * 4 + r;
                Cf[(size_t)row * N + col] =
                    acc[i][j][r] + bvl + resid[(size_t)row * N + col];
            }
        }
    }
}

// ---------------------------------------------------------------------------
// MFMA flash attention, S^T formulation, 128 q-rows per block (2 strips per
// wave). K/V LDS double-buffered, one barrier per kb.
// Round 6: SPLIT the (qt, 15-qt) pairing -> one q-tile per block, grid 1024.
// Rationale: grid 512 = exactly 2 blocks/CU while LDS (51.2 KB) allows 3;
// the declared (256,3) occupancy was unreachable by GRID SIZE. 1024 variable-
// length blocks (2qt+2 iters) pack at 3/CU; longest blocks (qt=15) are
// dispatched first (qt = 15 - id>>6) for tail packing. XCD locality kept:
// all qt-blocks of one (b,h) share id mod 8.
//  - raw v_exp_f32 inline asm; v_cvt_pk_bf16_f32 P-pack; setprio(1) on MFMA.
// ---------------------------------------------------------------------------
#define PSP 72
__global__ __launch_bounds__(256, 3) void flash_mfma(
    const ushort* __restrict__ Q, const ushort* __restrict__ K,
    const ushort* __restrict__ VtG, const float* __restrict__ mask,
    ushort* __restrict__ O)
{
    const int id = blockIdx.x;
    const int qt = 15 - (id >> 6);   // q tile (longest first)
    const int hb = id & 63;          // xcd = id % 8 under round-robin
    const int h = hb & 15, b = hb >> 4;
    __shared__ ushort Ks[2][64 * 64];    // [key][d], swizzled 16B chunks
    __shared__ ushort Vt[2][64 * 64];    // [d][key], swizzled 16B chunks
    __shared__ ushort Ps[128 * PSP];     // [q][key], wave-private strips
    const int tid = threadIdx.x;
    const int lane = tid & 63, wave = tid >> 6;
    const int fr = lane & 15, quad = lane >> 4;
    const int srow = tid >> 3;
    const int sc8 = tid & 7;
    const int g8 = sc8 ^ (srow & 7);
    const int swf = fr & 7;

    const ushort* gK0 = K + (size_t)(b * SEQ) * D + h * HD + (size_t)srow * D + g8 * 8;
    const ushort* gK1 = gK0 + (size_t)32 * D;
    const ushort* gV0 = VtG + ((size_t)(b * NH + h) * HD + srow) * SEQ + g8 * 8;
    const ushort* gV1 = gV0 + (size_t)32 * SEQ;
    const float* mrow = mask + (size_t)b * SEQ;
    const float SCALE2 = 0.125f * LOG2E;
    const float MASKC = -10000.0f * LOG2E;

    const int q0 = qt * 128;
    // Q B-fragments for both strips, straight from global
    bf16x8 qf[2][2];
#pragma unroll
    for (int s = 0; s < 2; ++s) {
        const ushort* qptr = Q + ((size_t)(b * SEQ + q0 + s * 64 + wave * 16 + fr)) * D
                               + h * HD + quad * 8;
        qf[s][0] = *(const bf16x8*)(qptr);
        qf[s][1] = *(const bf16x8*)(qptr + 32);
    }

    f32x4 oacc[2][4] = {};
    float lsum[2][4] = {};
    const int nkb = 2 * qt + 2;

    // prologue: stage kb=0 into buffer 0
    gl_lds16(gK0, &Ks[0][wave * 512]);
    gl_lds16(gK1, &Ks[0][2048 + wave * 512]);
    gl_lds16(gV0, &Vt[0][wave * 512]);
    gl_lds16(gV1, &Vt[0][2048 + wave * 512]);
    __syncthreads();

    for (int kb = 0; kb < nkb; ++kb) {
        const int cur = kb & 1;
        if (kb + 1 < nkb) {
            const int nxt = cur ^ 1;
            gl_lds16(gK0 + (size_t)(kb + 1) * 64 * D, &Ks[nxt][wave * 512]);
            gl_lds16(gK1 + (size_t)(kb + 1) * 64 * D, &Ks[nxt][2048 + wave * 512]);
            gl_lds16(gV0 + (kb + 1) * 64, &Vt[nxt][wave * 512]);
            gl_lds16(gV1 + (kb + 1) * 64, &Vt[nxt][2048 + wave * 512]);
        }
        f32x4 mv[4];
#pragma unroll
        for (int jt = 0; jt < 4; ++jt)
            mv[jt] = ((const f32x4*)(mrow + kb * 64))[jt * 4 + quad];

        const bool s0act = (kb <= 2 * qt);      // strip0 active (wave-uniform)

        // ---- S^T = K·Q^T for both strips (K frags shared) ----
        f32x4 sacc[2][4] = {};
        __builtin_amdgcn_s_setprio(1);
#pragma unroll
        for (int jt = 0; jt < 4; ++jt) {
            const int rb = (jt * 16 + fr) * 64;
            bf16x8 kf0 = *(const bf16x8*)&Ks[cur][rb + ((quad) ^ swf) * 8];
            bf16x8 kf1 = *(const bf16x8*)&Ks[cur][rb + ((4 + quad) ^ swf) * 8];
            sacc[0][jt] = __builtin_amdgcn_mfma_f32_16x16x32_bf16(kf0, qf[0][0], sacc[0][jt], 0, 0, 0);
            sacc[0][jt] = __builtin_amdgcn_mfma_f32_16x16x32_bf16(kf1, qf[0][1], sacc[0][jt], 0, 0, 0);
            sacc[1][jt] = __builtin_amdgcn_mfma_f32_16x16x32_bf16(kf0, qf[1][0], sacc[1][jt], 0, 0, 0);
            sacc[1][jt] = __builtin_amdgcn_mfma_f32_16x16x32_bf16(kf1, qf[1][1], sacc[1][jt], 0, 0, 0);
        }
        __builtin_amdgcn_s_setprio(0);

        // ---- softmax (fixed-max, raw v_exp_f32, cvt_pk bf16 P) ----
        float padd[4][4];
#pragma unroll
        for (int jt = 0; jt < 4; ++jt)
#pragma unroll
            for (int r = 0; r < 4; ++r)
                padd[jt][r] = fmaf(mv[jt][r], -MASKC, MASKC);
        const int ql = wave * 16 + fr;
#pragma unroll
        for (int s = 0; s < 2; ++s) {
            if (s == 0 && !s0act) continue;
            const bool diag = (kb == 2 * qt + s);
#pragma unroll
            for (int jt = 0; jt < 4; ++jt) {
                float p[4];
#pragma unroll
                for (int r = 0; r < 4; ++r) {
                    float v = fmaf(sacc[s][jt][r], SCALE2, padd[jt][r]);
                    if (diag) {
                        int keyl = jt * 16 + quad * 4 + r;
                        v = (keyl > ql) ? -1e30f : v;
                    }
                    float e = exp2_raw(v);
                    p[r] = e;
                    lsum[s][r] += e;
                }
                uint w0, w1;
                asm("v_cvt_pk_bf16_f32 %0, %1, %2" : "=v"(w0) : "v"(p[0]), "v"(p[1]));
                asm("v_cvt_pk_bf16_f32 %0, %1, %2" : "=v"(w1) : "v"(p[2]), "v"(p[3]));
                union { uint2 u; ushort4 us; } pu;
                pu.u.x = w0; pu.u.y = w1;
                *(ushort4*)&Ps[(s * 64 + wave * 16 + fr) * PSP + jt * 16 + quad * 4] = pu.us;
            }
        }
        // Ps strips are wave-private: no barrier needed.

        // ---- O += P·V (V frags shared across strips) ----
        bf16x8 pa[2][2];
#pragma unroll
        for (int s = 0; s < 2; ++s) {
            pa[s][0] = *(const bf16x8*)&Ps[(s * 64 + wave * 16 + fr) * PSP + quad * 8];
            pa[s][1] = *(const bf16x8*)&Ps[(s * 64 + wave * 16 + fr) * PSP + 32 + quad * 8];
        }
        __builtin_amdgcn_s_setprio(1);
#pragma unroll
        for (int dt = 0; dt < 4; ++dt) {
            const int rb = (dt * 16 + fr) * 64;
            bf16x8 vf0 = *(const bf16x8*)&Vt[cur][rb + ((quad) ^ swf) * 8];
            bf16x8 vf1 = *(const bf16x8*)&Vt[cur][rb + ((4 + quad) ^ swf) * 8];
            if (s0act) {
                oacc[0][dt] = __builtin_amdgcn_mfma_f32_16x16x32_bf16(pa[0][0], vf0, oacc[0][dt], 0, 0, 0);
                oacc[0][dt] = __builtin_amdgcn_mfma_f32_16x16x32_bf16(pa[0][1], vf1, oacc[0][dt], 0, 0, 0);
            }
            oacc[1][dt] = __builtin_amdgcn_mfma_f32_16x16x32_bf16(pa[1][0], vf0, oacc[1][dt], 0, 0, 0);
            oacc[1][dt] = __builtin_amdgcn_mfma_f32_16x16x32_bf16(pa[1][1], vf1, oacc[1][dt], 0, 0, 0);
        }
        __builtin_amdgcn_s_setprio(0);
        __syncthreads();   // drains prefetch vmcnt + all LDS reads of buf[cur]
    }

    // ---- finalize both strips ----
#pragma unroll
    for (int s = 0; s < 2; ++s) {
        float lt = (lsum[s][0] + lsum[s][1]) + (lsum[s][2] + lsum[s][3]);
        lt += __shfl_xor(lt, 16, 64);
        lt += __shfl_xor(lt, 32, 64);
        float linv[4];
#pragma unroll
        for (int r = 0; r < 4; ++r)
            linv[r] = 1.0f / __shfl(lt, quad * 4 + r, 64);
#pragma unroll
        for (int dt = 0; dt < 4; ++dt)
#pragma unroll
            for (int r = 0; r < 4; ++r) {
                int q = q0 + s * 64 + wave * 16 + quad * 4 + r;
                O[((size_t)(b * SEQ + q)) * D + h * HD + dt * 16 + fr] =
                    f2bf(oacc[s][dt][r] * linv[r]);
            }
    }
}

// ---------------------------------------------------------------------------
extern "C" void kernel_launch(void* const* d_in, const int* in_sizes, int n_in,
                              void* d_out, int out_size, void* d_ws, size_t ws_size,
                              hipStream_t stream)
{
    const float* x     = (const float*)d_in[0];
    const float* amask = (const float*)d_in[1];
    const float* Wq    = (const float*)d_in[2];
    const float* bq    = (const float*)d_in[3];
    const float* Wk    = (const float*)d_in[4];
    const float* bk    = (const float*)d_in[5];
    const float* Wv    = (const float*)d_in[6];
    const float* bv    = (const float*)d_in[7];
    const float* Wo    = (const float*)d_in[8];
    const float* bo    = (const float*)d_in[9];
    const float* gamma = (const float*)d_in[10];
    const float* beta  = (const float*)d_in[11];
    float* out = (float*)d_out;

    const size_t MROWS = (size_t)BATCH * SEQ;  // 8192
    const size_t MB = 1024 * 1024;
    char* ws = (char*)d_ws;
    ushort* Qb    = (ushort*)(ws);             // 16 MB bf16 [B,S,D]
    ushort* Kb    = (ushort*)(ws + 16 * MB);   // 16 MB [B,S,D]
    ushort* Vtb   = (ushort*)(ws + 32 * MB);   // 16 MB [B,H,D,S]
    ushort* xn_bf = (ushort*)(ws + 48 * MB);   // 16 MB (reused as attn_bf)
    ushort* Wq_bf = (ushort*)(ws + 64 * MB);   // Wq,Wk,Wv,Wo contiguous
    ushort* Wo_bf = (ushort*)(ws + 70 * MB);
    ushort* attn_bf = xn_bf;

    // fused LN + weight-convert: 8192 LN blocks + 4096 cvt blocks
    prep<<<dim3((unsigned)(MROWS + 4096)), 256, 0, stream>>>(
        x, gamma, beta, xn_bf, Wq, Wk, Wv, Wo, Wq_bf);

    gemm_qkv<<<dim3(24, 64), 256, 0, stream>>>(xn_bf, Wq_bf, bq, bk, bv,
                                               Qb, Kb, Vtb, (int)MROWS, D);

    flash_mfma<<<dim3(1024), 256, 0, stream>>>(Qb, Kb, Vtb, amask, attn_bf);

    gemm_out<<<dim3(8, 64), 256, 0, stream>>>(attn_bf, Wo_bf, bo, x, out,
                                              (int)MROWS, D, D);
}

// Round 7
// 285.027 us; speedup vs baseline: 1.0051x; 1.0051x over previous
//
#include <hip/hip_runtime.h>

#define D 1024
#define NH 16
#define HD 64
#define SEQ 2048
#define BATCH 4
#define LN_EPS 1e-5f
#define LOG2E 1.44269504088896f

typedef __attribute__((ext_vector_type(8))) __bf16 bf16x8;
typedef __attribute__((ext_vector_type(4))) float f32x4;

__device__ __forceinline__ ushort f2bf(float f) {
    union { float f; uint u; } c; c.f = f;
    uint u = c.u + 0x7fffu + ((c.u >> 16) & 1u);   // RNE
    return (ushort)(u >> 16);
}

// async global->LDS DMA, 16B per lane; LDS dest = wave-uniform base + lane*16
__device__ __forceinline__ void gl_lds16(const ushort* g, ushort* lds) {
    __builtin_amdgcn_global_load_lds(
        (const __attribute__((address_space(1))) void*)g,
        (__attribute__((address_space(3))) void*)lds, 16, 0, 0);
}

// raw v_exp_f32: D = 2^S0 (cdna4_isa §3). Single VALU inst, no OCML path.
__device__ __forceinline__ float exp2_raw(float v) {
    float e;
    asm("v_exp_f32 %0, %1" : "=v"(e) : "v"(v));
    return e;
}

// ---------------------------------------------------------------------------
// prep: fused {LayerNorm rows} + {fp32->bf16 convert of 4 weight matrices}.
// ---------------------------------------------------------------------------
__global__ __launch_bounds__(256) void prep(
    const float* __restrict__ x, const float* __restrict__ gamma,
    const float* __restrict__ beta, ushort* __restrict__ xn,
    const float* __restrict__ w0, const float* __restrict__ w1,
    const float* __restrict__ w2, const float* __restrict__ w3,
    ushort* __restrict__ wout)
{
    const int bid = blockIdx.x;
    const int tid = threadIdx.x;
    if (bid < BATCH * SEQ) {
        // ---- LayerNorm ----
        int row = bid;
        float4 v = ((const float4*)(x + (size_t)row * D))[tid];
        float s = v.x + v.y + v.z + v.w;
#pragma unroll
        for (int off = 32; off > 0; off >>= 1) s += __shfl_down(s, off, 64);
        __shared__ float red1[4], red2[4];
        int wid = tid >> 6, lane = tid & 63;
        if (lane == 0) red1[wid] = s;
        __syncthreads();
        float mean = (red1[0] + red1[1] + red1[2] + red1[3]) * (1.0f / D);
        float dx = v.x - mean, dy = v.y - mean, dz = v.z - mean, dw = v.w - mean;
        float ss = dx * dx + dy * dy + dz * dz + dw * dw;
#pragma unroll
        for (int off = 32; off > 0; off >>= 1) ss += __shfl_down(ss, off, 64);
        if (lane == 0) red2[wid] = ss;
        __syncthreads();
        float var = (red2[0] + red2[1] + red2[2] + red2[3]) * (1.0f / D);
        float rstd = rsqrtf(var + LN_EPS);
        float4 g = ((const float4*)gamma)[tid];
        float4 b = ((const float4*)beta)[tid];
        ushort4 o;
        o.x = f2bf(dx * rstd * g.x + b.x);
        o.y = f2bf(dy * rstd * g.y + b.y);
        o.z = f2bf(dz * rstd * g.z + b.z);
        o.w = f2bf(dw * rstd * g.w + b.w);
        ((ushort4*)(xn + (size_t)row * D))[tid] = o;
    } else {
        // ---- weight convert ----
        const int n = D * D;
        int p = bid - BATCH * SEQ;
        int sel = p >> 10;                 // 0..3
        int xblk = p & 1023;
        const float* in = sel == 0 ? w0 : (sel == 1 ? w1 : (sel == 2 ? w2 : w3));
        int i = (xblk * 256 + tid) * 4;
        float4 v = *(const float4*)(in + i);
        ushort4 o;
        o.x = f2bf(v.x); o.y = f2bf(v.y); o.z = f2bf(v.z); o.w = f2bf(v.w);
        *(ushort4*)(wout + (size_t)sel * n + i) = o;
    }
}

// ---------------------------------------------------------------------------
// GEMM round 7: 128x128 tile, BK=32, dbuf LDS = 32 KB -> 5 blocks/CU.
// Combines dbuf prefetch (round 1) with round-0's 5-block inter-block overlap:
// a block parked at the K-step barrier is covered by 4 other resident blocks.
// Per K-step: 4 gl_lds (2A+2W), 8 ds_read_b128, 16 MFMA (K=32, no kh loop),
// one __syncthreads. Swizzle over 4 chunks/row: chunk c ^ ((row>>1)&3)
// ((row&3) would leave same-bank-set rows on 2 chunks -> 4-way conflict;
// (row>>1)&3 cycles all 4 -> 2-way = free).
// ---------------------------------------------------------------------------
#define BM 128
#define BK2 32

// ---------------------------------------------------------------------------
// Fused QKV GEMM: W = stacked [Wq;Wk;Wv] = [3072][1024] bf16. Grid (24, 64).
// Region 0->Q, 1->K row-major bf16; region 2 -> V transposed to [B,H,D,S].
// ---------------------------------------------------------------------------
__global__ __launch_bounds__(256) void gemm_qkv(
    const ushort* __restrict__ A,    // [M,1024] bf16
    const ushort* __restrict__ W,    // [3072,1024] bf16
    const float* __restrict__ bq, const float* __restrict__ bk,
    const float* __restrict__ bv,
    ushort* __restrict__ Cq, ushort* __restrict__ Ck,
    ushort* __restrict__ CvT,
    int M, int K)
{
    __shared__ ushort As[2][BM * BK2];   // 2 x 8 KB
    __shared__ ushort Ws[2][BM * BK2];
    const int tid = threadIdx.x;
    const int lane = tid & 63;
    const int wave = tid >> 6;
    const int wr = wave >> 1, wc = wave & 1;
    const int m0 = blockIdx.y * BM;
    const int n0g = blockIdx.x * BM;
    const int region = n0g >> 10;
    const int n0l = n0g & 1023;
    const float* bias = region == 0 ? bq : (region == 1 ? bk : bv);
    const int fr = lane & 15, quad = lane >> 4;
    const int r4 = lane >> 2, c4 = lane & 3;          // 4 lanes/row, 16 rows/instr
    const int gc4 = c4 ^ ((r4 >> 1) & 3);             // swizzled global chunk
    const int swf = (fr >> 1) & 3;

    const ushort* gA = A + (size_t)(m0 + wave * 32 + r4) * K + gc4 * 8;
    const ushort* gW = W + (size_t)(n0g + wave * 32 + r4) * K + gc4 * 8;
    const int ldso = (wave * 32) * BK2;

    f32x4 acc[4][4] = {};

    // prologue: stage K-tile 0 into buffer 0
#pragma unroll
    for (int t = 0; t < 2; ++t) {
        gl_lds16(gA + (size_t)t * 16 * K, &As[0][ldso + t * 16 * BK2]);
        gl_lds16(gW + (size_t)t * 16 * K, &Ws[0][ldso + t * 16 * BK2]);
    }
    __syncthreads();

    for (int k0 = 0; k0 < K; k0 += BK2) {
        const int cur = (k0 >> 5) & 1;
        if (k0 + BK2 < K) {
            const int nxt = cur ^ 1;
#pragma unroll
            for (int t = 0; t < 2; ++t) {
                gl_lds16(gA + (size_t)t * 16 * K + k0 + BK2, &As[nxt][ldso + t * 16 * BK2]);
                gl_lds16(gW + (size_t)t * 16 * K + k0 + BK2, &Ws[nxt][ldso + t * 16 * BK2]);
            }
        }
        bf16x8 af[4], bf[4];
        const int co = (quad ^ swf) * 8;
#pragma unroll
        for (int i = 0; i < 4; ++i) {
            af[i] = *(const bf16x8*)&As[cur][(wr * 64 + i * 16 + fr) * BK2 + co];
            bf[i] = *(const bf16x8*)&Ws[cur][(wc * 64 + i * 16 + fr) * BK2 + co];
        }
#pragma unroll
        for (int i = 0; i < 4; ++i)
#pragma unroll
            for (int j = 0; j < 4; ++j)
                acc[i][j] = __builtin_amdgcn_mfma_f32_16x16x32_bf16(af[i], bf[j], acc[i][j], 0, 0, 0);
        __syncthreads();   // drains prefetch vmcnt + fragment lgkm; one barrier/K-step
    }

#pragma unroll
    for (int j = 0; j < 4; ++j) {
        int col = n0l + wc * 64 + j * 16 + fr;
        float bvl = bias[col];
#pragma unroll
        for (int i = 0; i < 4; ++i) {
#pragma unroll
            for (int r = 0; r < 4; ++r) {
                int row = m0 + wr * 64 + i * 16 + quad * 4 + r;
                ushort hv = f2bf(acc[i][j][r] + bvl);
                if (region == 0) {
                    Cq[(size_t)row * 1024 + col] = hv;
                } else if (region == 1) {
                    Ck[(size_t)row * 1024 + col] = hv;
                } else {
                    int bb = row >> 11, s = row & 2047;
                    int hh = col >> 6, d = col & 63;
                    CvT[(((size_t)bb * NH + hh) * HD + d) * SEQ + s] = hv;
                }
            }
        }
    }
}

// ---------------------------------------------------------------------------
// Output projection GEMM (+bias +fp32 residual), same BK=32 dbuf structure.
// ---------------------------------------------------------------------------
__global__ __launch_bounds__(256) void gemm_out(
    const ushort* __restrict__ A, const ushort* __restrict__ W,
    const float* __restrict__ bias, const float* __restrict__ resid,
    float* __restrict__ Cf, int M, int N, int K)
{
    __shared__ ushort As[2][BM * BK2];
    __shared__ ushort Ws[2][BM * BK2];
    const int tid = threadIdx.x;
    const int lane = tid & 63;
    const int wave = tid >> 6;
    const int wr = wave >> 1, wc = wave & 1;
    const int m0 = blockIdx.y * BM, n0 = blockIdx.x * BM;
    const int fr = lane & 15, quad = lane >> 4;
    const int r4 = lane >> 2, c4 = lane & 3;
    const int gc4 = c4 ^ ((r4 >> 1) & 3);
    const int swf = (fr >> 1) & 3;

    const ushort* gA = A + (size_t)(m0 + wave * 32 + r4) * K + gc4 * 8;
    const ushort* gW = W + (size_t)(n0 + wave * 32 + r4) * K + gc4 * 8;
    const int ldso = (wave * 32) * BK2;

    f32x4 acc[4][4] = {};

    // prologue: stage K-tile 0 into buffer 0
#pragma unroll
    for (int t = 0; t < 2; ++t) {
        gl_lds16(gA + (size_t)t * 16 * K, &As[0][ldso + t * 16 * BK2]);
        gl_lds16(gW + (size_t)t * 16 * K, &Ws[0][ldso + t * 16 * BK2]);
    }
    __syncthreads();

    for (int k0 = 0; k0 < K; k0 += BK2) {
        const int cur = (k0 >> 5) & 1;
        if (k0 + BK2 < K) {
            const int nxt = cur ^ 1;
#pragma unroll
            for (int t = 0; t < 2; ++t) {
                gl_lds16(gA + (size_t)t * 16 * K + k0 + BK2, &As[nxt][ldso + t * 16 * BK2]);
                gl_lds16(gW + (size_t)t * 16 * K + k0 + BK2, &Ws[nxt][ldso + t * 16 * BK2]);
            }
        }
        bf16x8 af[4], bf[4];
        const int co = (quad ^ swf) * 8;
#pragma unroll
        for (int i = 0; i < 4; ++i) {
            af[i] = *(const bf16x8*)&As[cur][(wr * 64 + i * 16 + fr) * BK2 + co];
            bf[i] = *(const bf16x8*)&Ws[cur][(wc * 64 + i * 16 + fr) * BK2 + co];
        }
#pragma unroll
        for (int i = 0; i < 4; ++i)
#pragma unroll
            for (int j = 0; j < 4; ++j)
                acc[i][j] = __builtin_amdgcn_mfma_f32_16x16x32_bf16(af[i], bf[j], acc[i][j], 0, 0, 0);
        __syncthreads();
    }

#pragma unroll
    for (int j = 0; j < 4; ++j) {
        int col = n0 + wc * 64 + j * 16 + fr;
        float bvl = bias[col];
#pragma unroll
        for (int i = 0; i < 4; ++i) {
#pragma unroll
            for (int r = 0; r < 4; ++r) {
                int row = m0 + wr * 64 + i * 16 + quad * 4 + r;
                Cf[(size_t)row * N + col] =
                    acc[i][j][r] + bvl + resid[(size_t)row * N + col];
            }
        }
    }
}

// ---------------------------------------------------------------------------
// MFMA flash attention, S^T formulation, 128 q-rows per block (2 strips per
// wave). K/V LDS double-buffered, one barrier per kb. (Round-5 verified form:
// paired q-tiles (qt, 15-qt), grid 512 — round-6 split regressed, reverted.)
//  - XCD-aware 1D grid: 8 bx-blocks sharing one (b,h) K/V stream -> same XCD.
//  - raw v_exp_f32 inline asm; v_cvt_pk_bf16_f32 P-pack; setprio(1) on MFMA.
// ---------------------------------------------------------------------------
#define PSP 72
__global__ __launch_bounds__(256, 3) void flash_mfma(
    const ushort* __restrict__ Q, const ushort* __restrict__ K,
    const ushort* __restrict__ VtG, const float* __restrict__ mask,
    ushort* __restrict__ O)
{
    const int id = blockIdx.x;
    const int bx = id >> 6;          // q-tile pair selector 0..7
    const int hb = id & 63;          // xcd = hb % 8 under round-robin
    const int h = hb & 15, b = hb >> 4;
    __shared__ ushort Ks[2][64 * 64];    // [key][d], swizzled 16B chunks
    __shared__ ushort Vt[2][64 * 64];    // [d][key], swizzled 16B chunks
    __shared__ ushort Ps[128 * PSP];     // [q][key], wave-private strips
    const int tid = threadIdx.x;
    const int lane = tid & 63, wave = tid >> 6;
    const int fr = lane & 15, quad = lane >> 4;
    const int srow = tid >> 3;
    const int sc8 = tid & 7;
    const int g8 = sc8 ^ (srow & 7);
    const int swf = fr & 7;

    const ushort* gK0 = K + (size_t)(b * SEQ) * D + h * HD + (size_t)srow * D + g8 * 8;
    const ushort* gK1 = gK0 + (size_t)32 * D;
    const ushort* gV0 = VtG + ((size_t)(b * NH + h) * HD + srow) * SEQ + g8 * 8;
    const ushort* gV1 = gV0 + (size_t)32 * SEQ;
    const float* mrow = mask + (size_t)b * SEQ;
    const float SCALE2 = 0.125f * LOG2E;
    const float MASKC = -10000.0f * LOG2E;

    for (int phase = 0; phase < 2; ++phase) {
        const int qt = phase ? (15 - bx) : bx;      // 128-row q tile
        const int q0 = qt * 128;
        // Q B-fragments for both strips, straight from global
        bf16x8 qf[2][2];
#pragma unroll
        for (int s = 0; s < 2; ++s) {
            const ushort* qptr = Q + ((size_t)(b * SEQ + q0 + s * 64 + wave * 16 + fr)) * D
                                   + h * HD + quad * 8;
            qf[s][0] = *(const bf16x8*)(qptr);
            qf[s][1] = *(const bf16x8*)(qptr + 32);
        }

        f32x4 oacc[2][4] = {};
        float lsum[2][4] = {};
        const int nkb = 2 * qt + 2;

        // prologue: stage kb=0 into buffer 0
        gl_lds16(gK0, &Ks[0][wave * 512]);
        gl_lds16(gK1, &Ks[0][2048 + wave * 512]);
        gl_lds16(gV0, &Vt[0][wave * 512]);
        gl_lds16(gV1, &Vt[0][2048 + wave * 512]);
        __syncthreads();

        for (int kb = 0; kb < nkb; ++kb) {
            const int cur = kb & 1;
            if (kb + 1 < nkb) {
                const int nxt = cur ^ 1;
                gl_lds16(gK0 + (size_t)(kb + 1) * 64 * D, &Ks[nxt][wave * 512]);
                gl_lds16(gK1 + (size_t)(kb + 1) * 64 * D, &Ks[nxt][2048 + wave * 512]);
                gl_lds16(gV0 + (kb + 1) * 64, &Vt[nxt][wave * 512]);
                gl_lds16(gV1 + (kb + 1) * 64, &Vt[nxt][2048 + wave * 512]);
            }
            f32x4 mv[4];
#pragma unroll
            for (int jt = 0; jt < 4; ++jt)
                mv[jt] = ((const f32x4*)(mrow + kb * 64))[jt * 4 + quad];

            const bool s0act = (kb <= 2 * qt);      // strip0 active (wave-uniform)

            // ---- S^T = K·Q^T for both strips (K frags shared) ----
            f32x4 sacc[2][4] = {};
            __builtin_amdgcn_s_setprio(1);
#pragma unroll
            for (int jt = 0; jt < 4; ++jt) {
                const int rb = (jt * 16 + fr) * 64;
                bf16x8 kf0 = *(const bf16x8*)&Ks[cur][rb + ((quad) ^ swf) * 8];
                bf16x8 kf1 = *(const bf16x8*)&Ks[cur][rb + ((4 + quad) ^ swf) * 8];
                sacc[0][jt] = __builtin_amdgcn_mfma_f32_16x16x32_bf16(kf0, qf[0][0], sacc[0][jt], 0, 0, 0);
                sacc[0][jt] = __builtin_amdgcn_mfma_f32_16x16x32_bf16(kf1, qf[0][1], sacc[0][jt], 0, 0, 0);
                sacc[1][jt] = __builtin_amdgcn_mfma_f32_16x16x32_bf16(kf0, qf[1][0], sacc[1][jt], 0, 0, 0);
                sacc[1][jt] = __builtin_amdgcn_mfma_f32_16x16x32_bf16(kf1, qf[1][1], sacc[1][jt], 0, 0, 0);
            }
            __builtin_amdgcn_s_setprio(0);

            // ---- softmax (fixed-max, raw v_exp_f32, cvt_pk bf16 P) ----
            float padd[4][4];
#pragma unroll
            for (int jt = 0; jt < 4; ++jt)
#pragma unroll
                for (int r = 0; r < 4; ++r)
                    padd[jt][r] = fmaf(mv[jt][r], -MASKC, MASKC);
            const int ql = wave * 16 + fr;
#pragma unroll
            for (int s = 0; s < 2; ++s) {
                if (s == 0 && !s0act) continue;
                const bool diag = (kb == 2 * qt + s);
#pragma unroll
                for (int jt = 0; jt < 4; ++jt) {
                    float p[4];
#pragma unroll
                    for (int r = 0; r < 4; ++r) {
                        float v = fmaf(sacc[s][jt][r], SCALE2, padd[jt][r]);
                        if (diag) {
                            int keyl = jt * 16 + quad * 4 + r;
                            v = (keyl > ql) ? -1e30f : v;
                        }
                        float e = exp2_raw(v);
                        p[r] = e;
                        lsum[s][r] += e;
                    }
                    uint w0, w1;
                    asm("v_cvt_pk_bf16_f32 %0, %1, %2" : "=v"(w0) : "v"(p[0]), "v"(p[1]));
                    asm("v_cvt_pk_bf16_f32 %0, %1, %2" : "=v"(w1) : "v"(p[2]), "v"(p[3]));
                    union { uint2 u; ushort4 us; } pu;
                    pu.u.x = w0; pu.u.y = w1;
                    *(ushort4*)&Ps[(s * 64 + wave * 16 + fr) * PSP + jt * 16 + quad * 4] = pu.us;
                }
            }
            // Ps strips are wave-private: no barrier needed.

            // ---- O += P·V (V frags shared across strips) ----
            bf16x8 pa[2][2];
#pragma unroll
            for (int s = 0; s < 2; ++s) {
                pa[s][0] = *(const bf16x8*)&Ps[(s * 64 + wave * 16 + fr) * PSP + quad * 8];
                pa[s][1] = *(const bf16x8*)&Ps[(s * 64 + wave * 16 + fr) * PSP + 32 + quad * 8];
            }
            __builtin_amdgcn_s_setprio(1);
#pragma unroll
            for (int dt = 0; dt < 4; ++dt) {
                const int rb = (dt * 16 + fr) * 64;
                bf16x8 vf0 = *(const bf16x8*)&Vt[cur][rb + ((quad) ^ swf) * 8];
                bf16x8 vf1 = *(const bf16x8*)&Vt[cur][rb + ((4 + quad) ^ swf) * 8];
                if (s0act) {
                    oacc[0][dt] = __builtin_amdgcn_mfma_f32_16x16x32_bf16(pa[0][0], vf0, oacc[0][dt], 0, 0, 0);
                    oacc[0][dt] = __builtin_amdgcn_mfma_f32_16x16x32_bf16(pa[0][1], vf1, oacc[0][dt], 0, 0, 0);
                }
                oacc[1][dt] = __builtin_amdgcn_mfma_f32_16x16x32_bf16(pa[1][0], vf0, oacc[1][dt], 0, 0, 0);
                oacc[1][dt] = __builtin_amdgcn_mfma_f32_16x16x32_bf16(pa[1][1], vf1, oacc[1][dt], 0, 0, 0);
            }
            __builtin_amdgcn_s_setprio(0);
            __syncthreads();   // drains prefetch vmcnt + all LDS reads of buf[cur]
        }

        // ---- finalize both strips ----
#pragma unroll
        for (int s = 0; s < 2; ++s) {
            float lt = (lsum[s][0] + lsum[s][1]) + (lsum[s][2] + lsum[s][3]);
            lt += __shfl_xor(lt, 16, 64);
            lt += __shfl_xor(lt, 32, 64);
            float linv[4];
#pragma unroll
            for (int r = 0; r < 4; ++r)
                linv[r] = 1.0f / __shfl(lt, quad * 4 + r, 64);
#pragma unroll
            for (int dt = 0; dt < 4; ++dt)
#pragma unroll
                for (int r = 0; r < 4; ++r) {
                    int q = q0 + s * 64 + wave * 16 + quad * 4 + r;
                    O[((size_t)(b * SEQ + q)) * D + h * HD + dt * 16 + fr] =
                        f2bf(oacc[s][dt][r] * linv[r]);
                }
        }
    }
}

// ---------------------------------------------------------------------------
extern "C" void kernel_launch(void* const* d_in, const int* in_sizes, int n_in,
                              void* d_out, int out_size, void* d_ws, size_t ws_size,
                              hipStream_t stream)
{
    const float* x     = (const float*)d_in[0];
    const float* amask = (const float*)d_in[1];
    const float* Wq    = (const float*)d_in[2];
    const float* bq    = (const float*)d_in[3];
    const float* Wk    = (const float*)d_in[4];
    const float* bk    = (const float*)d_in[5];
    const float* Wv    = (const float*)d_in[6];
    const float* bv    = (const float*)d_in[7];
    const float* Wo    = (const float*)d_in[8];
    const float* bo    = (const float*)d_in[9];
    const float* gamma = (const float*)d_in[10];
    const float* beta  = (const float*)d_in[11];
    float* out = (float*)d_out;

    const size_t MROWS = (size_t)BATCH * SEQ;  // 8192
    const size_t MB = 1024 * 1024;
    char* ws = (char*)d_ws;
    ushort* Qb    = (ushort*)(ws);             // 16 MB bf16 [B,S,D]
    ushort* Kb    = (ushort*)(ws + 16 * MB);   // 16 MB [B,S,D]
    ushort* Vtb   = (ushort*)(ws + 32 * MB);   // 16 MB [B,H,D,S]
    ushort* xn_bf = (ushort*)(ws + 48 * MB);   // 16 MB (reused as attn_bf)
    ushort* Wq_bf = (ushort*)(ws + 64 * MB);   // Wq,Wk,Wv,Wo contiguous
    ushort* Wo_bf = (ushort*)(ws + 70 * MB);
    ushort* attn_bf = xn_bf;

    // fused LN + weight-convert: 8192 LN blocks + 4096 cvt blocks
    prep<<<dim3((unsigned)(MROWS + 4096)), 256, 0, stream>>>(
        x, gamma, beta, xn_bf, Wq, Wk, Wv, Wo, Wq_bf);

    gemm_qkv<<<dim3(24, 64), 256, 0, stream>>>(xn_bf, Wq_bf, bq, bk, bv,
                                               Qb, Kb, Vtb, (int)MROWS, D);

    flash_mfma<<<dim3(512), 256, 0, stream>>>(Qb, Kb, Vtb, amask, attn_bf);

    gemm_out<<<dim3(8, 64), 256, 0, stream>>>(attn_bf, Wo_bf, bo, x, out,
                                              (int)MROWS, D, D);
}

// Round 8
// 282.695 us; speedup vs baseline: 1.0134x; 1.0082x over previous
//
#include <hip/hip_runtime.h>

#define D 1024
#define NH 16
#define HD 64
#define SEQ 2048
#define BATCH 4
#define LN_EPS 1e-5f
#define LOG2E 1.44269504088896f

typedef __attribute__((ext_vector_type(8))) __bf16 bf16x8;
typedef __attribute__((ext_vector_type(4))) float f32x4;

__device__ __forceinline__ ushort f2bf(float f) {
    union { float f; uint u; } c; c.f = f;
    uint u = c.u + 0x7fffu + ((c.u >> 16) & 1u);   // RNE
    return (ushort)(u >> 16);
}

// async global->LDS DMA, 16B per lane; LDS dest = wave-uniform base + lane*16
__device__ __forceinline__ void gl_lds16(const ushort* g, ushort* lds) {
    __builtin_amdgcn_global_load_lds(
        (const __attribute__((address_space(1))) void*)g,
        (__attribute__((address_space(3))) void*)lds, 16, 0, 0);
}

// raw v_exp_f32: D = 2^S0 (cdna4_isa §3). Single VALU inst, no OCML path.
__device__ __forceinline__ float exp2_raw(float v) {
    float e;
    asm("v_exp_f32 %0, %1" : "=v"(e) : "v"(v));
    return e;
}

// ---------------------------------------------------------------------------
// prep: fused {LayerNorm rows} + {fp32->bf16 convert of 4 weight matrices}.
// ---------------------------------------------------------------------------
__global__ __launch_bounds__(256) void prep(
    const float* __restrict__ x, const float* __restrict__ gamma,
    const float* __restrict__ beta, ushort* __restrict__ xn,
    const float* __restrict__ w0, const float* __restrict__ w1,
    const float* __restrict__ w2, const float* __restrict__ w3,
    ushort* __restrict__ wout)
{
    const int bid = blockIdx.x;
    const int tid = threadIdx.x;
    if (bid < BATCH * SEQ) {
        // ---- LayerNorm ----
        int row = bid;
        float4 v = ((const float4*)(x + (size_t)row * D))[tid];
        float s = v.x + v.y + v.z + v.w;
#pragma unroll
        for (int off = 32; off > 0; off >>= 1) s += __shfl_down(s, off, 64);
        __shared__ float red1[4], red2[4];
        int wid = tid >> 6, lane = tid & 63;
        if (lane == 0) red1[wid] = s;
        __syncthreads();
        float mean = (red1[0] + red1[1] + red1[2] + red1[3]) * (1.0f / D);
        float dx = v.x - mean, dy = v.y - mean, dz = v.z - mean, dw = v.w - mean;
        float ss = dx * dx + dy * dy + dz * dz + dw * dw;
#pragma unroll
        for (int off = 32; off > 0; off >>= 1) ss += __shfl_down(ss, off, 64);
        if (lane == 0) red2[wid] = ss;
        __syncthreads();
        float var = (red2[0] + red2[1] + red2[2] + red2[3]) * (1.0f / D);
        float rstd = rsqrtf(var + LN_EPS);
        float4 g = ((const float4*)gamma)[tid];
        float4 b = ((const float4*)beta)[tid];
        ushort4 o;
        o.x = f2bf(dx * rstd * g.x + b.x);
        o.y = f2bf(dy * rstd * g.y + b.y);
        o.z = f2bf(dz * rstd * g.z + b.z);
        o.w = f2bf(dw * rstd * g.w + b.w);
        ((ushort4*)(xn + (size_t)row * D))[tid] = o;
    } else {
        // ---- weight convert ----
        const int n = D * D;
        int p = bid - BATCH * SEQ;
        int sel = p >> 10;                 // 0..3
        int xblk = p & 1023;
        const float* in = sel == 0 ? w0 : (sel == 1 ? w1 : (sel == 2 ? w2 : w3));
        int i = (xblk * 256 + tid) * 4;
        float4 v = *(const float4*)(in + i);
        ushort4 o;
        o.x = f2bf(v.x); o.y = f2bf(v.y); o.z = f2bf(v.z); o.w = f2bf(v.w);
        *(ushort4*)(wout + (size_t)sel * n + i) = o;
    }
}

// ---------------------------------------------------------------------------
// GEMM round 8: 128x128 tile, BK=64 dbuf (round-5 verified geometry) with
// COUNTED vmcnt (round-4 verified-correct sync structure, T4):
//   issue 8 loads(tile k+1) -> buf[nxt]; vmcnt(8)   // waits tile k only;
//                                                   // k+1's stay in flight
//   s_barrier (+sched_barrier)                      // tile k visible to all
//   compute 32 MFMA from buf[cur]
//   lgkmcnt(0); s_barrier                           // WAR: reads done before
//                                                   // next iter overwrites
// vs round-5's single __syncthreads, which drained vmcnt(0) — forcing the
// JUST-ISSUED prefetch to land with only ~350cy compute as cover (~500cy
// exposed/step -> MfmaUtil 23.5%). Counted form gives each tile a full
// iteration of cover. BK=32 (round 7) and 256^2 (round 4) both regressed;
// this combines the two proven halves.
// ---------------------------------------------------------------------------
#define BM 128
#define BKK 64

// ---------------------------------------------------------------------------
// Fused QKV GEMM: W = stacked [Wq;Wk;Wv] = [3072][1024] bf16. Grid (24, 64).
// Region 0->Q, 1->K row-major bf16; region 2 -> V transposed to [B,H,D,S].
// ---------------------------------------------------------------------------
__global__ __launch_bounds__(256) void gemm_qkv(
    const ushort* __restrict__ A,    // [M,1024] bf16
    const ushort* __restrict__ W,    // [3072,1024] bf16
    const float* __restrict__ bq, const float* __restrict__ bk,
    const float* __restrict__ bv,
    ushort* __restrict__ Cq, ushort* __restrict__ Ck,
    ushort* __restrict__ CvT,
    int M, int K)
{
    __shared__ ushort As[2][BM * BKK];   // 2 x 16 KB
    __shared__ ushort Ws[2][BM * BKK];
    const int tid = threadIdx.x;
    const int lane = tid & 63;
    const int wave = tid >> 6;
    const int wr = wave >> 1, wc = wave & 1;
    const int m0 = blockIdx.y * BM;
    const int n0g = blockIdx.x * BM;
    const int region = n0g >> 10;
    const int n0l = n0g & 1023;
    const float* bias = region == 0 ? bq : (region == 1 ? bk : bv);
    const int fr = lane & 15, quad = lane >> 4;
    const int r8 = lane >> 3, c8 = lane & 7;
    const int gc8 = c8 ^ r8;               // swizzled global chunk
    const int swf = fr & 7;

    const ushort* gA = A + (size_t)(m0 + wave * 32 + r8) * K + gc8 * 8;
    const ushort* gW = W + (size_t)(n0g + wave * 32 + r8) * K + gc8 * 8;
    const int ldso = (wave * 32) * BKK;

    f32x4 acc[4][4] = {};

    // prologue: stage tile 0 into buffer 0 (8 loads, left in flight)
#pragma unroll
    for (int t = 0; t < 4; ++t) {
        gl_lds16(gA + (size_t)t * 8 * K, &As[0][ldso + t * 8 * BKK]);
        gl_lds16(gW + (size_t)t * 8 * K, &Ws[0][ldso + t * 8 * BKK]);
    }

    const int NT = K / BKK;               // 16
    for (int kt = 0; kt < NT; ++kt) {
        const int cur = kt & 1;
        if (kt + 1 < NT) {
            const int nxt = cur ^ 1;
            const int k1 = (kt + 1) * BKK;
#pragma unroll
            for (int t = 0; t < 4; ++t) {
                gl_lds16(gA + (size_t)t * 8 * K + k1, &As[nxt][ldso + t * 8 * BKK]);
                gl_lds16(gW + (size_t)t * 8 * K + k1, &Ws[nxt][ldso + t * 8 * BKK]);
            }
            // wait only for tile kt's 8 loads; kt+1's stay in flight
            asm volatile("s_waitcnt vmcnt(8)" ::: "memory");
        } else {
            asm volatile("s_waitcnt vmcnt(0)" ::: "memory");
        }
        __builtin_amdgcn_s_barrier();
        __builtin_amdgcn_sched_barrier(0);   // no LDS read hoists above barrier
#pragma unroll
        for (int kh = 0; kh < 2; ++kh) {
            bf16x8 af[4], bf[4];
            const int co = ((kh * 4 + quad) ^ swf) * 8;
#pragma unroll
            for (int i = 0; i < 4; ++i) {
                af[i] = *(const bf16x8*)&As[cur][(wr * 64 + i * 16 + fr) * BKK + co];
                bf[i] = *(const bf16x8*)&Ws[cur][(wc * 64 + i * 16 + fr) * BKK + co];
            }
#pragma unroll
            for (int i = 0; i < 4; ++i)
#pragma unroll
                for (int j = 0; j < 4; ++j)
                    acc[i][j] = __builtin_amdgcn_mfma_f32_16x16x32_bf16(af[i], bf[j], acc[i][j], 0, 0, 0);
        }
        asm volatile("s_waitcnt lgkmcnt(0)" ::: "memory");
        __builtin_amdgcn_s_barrier();        // buf[cur] readers done before overwrite
    }

#pragma unroll
    for (int j = 0; j < 4; ++j) {
        int col = n0l + wc * 64 + j * 16 + fr;
        float bvl = bias[col];
#pragma unroll
        for (int i = 0; i < 4; ++i) {
#pragma unroll
            for (int r = 0; r < 4; ++r) {
                int row = m0 + wr * 64 + i * 16 + quad * 4 + r;
                ushort hv = f2bf(acc[i][j][r] + bvl);
                if (region == 0) {
                    Cq[(size_t)row * 1024 + col] = hv;
                } else if (region == 1) {
                    Ck[(size_t)row * 1024 + col] = hv;
                } else {
                    int bb = row >> 11, s = row & 2047;
                    int hh = col >> 6, d = col & 63;
                    CvT[(((size_t)bb * NH + hh) * HD + d) * SEQ + s] = hv;
                }
            }
        }
    }
}

// ---------------------------------------------------------------------------
// Output projection GEMM (+bias +fp32 residual), same counted-vmcnt structure.
// ---------------------------------------------------------------------------
__global__ __launch_bounds__(256) void gemm_out(
    const ushort* __restrict__ A, const ushort* __restrict__ W,
    const float* __restrict__ bias, const float* __restrict__ resid,
    float* __restrict__ Cf, int M, int N, int K)
{
    __shared__ ushort As[2][BM * BKK];
    __shared__ ushort Ws[2][BM * BKK];
    const int tid = threadIdx.x;
    const int lane = tid & 63;
    const int wave = tid >> 6;
    const int wr = wave >> 1, wc = wave & 1;
    const int m0 = blockIdx.y * BM, n0 = blockIdx.x * BM;
    const int fr = lane & 15, quad = lane >> 4;
    const int r8 = lane >> 3, c8 = lane & 7;
    const int gc8 = c8 ^ r8;
    const int swf = fr & 7;

    const ushort* gA = A + (size_t)(m0 + wave * 32 + r8) * K + gc8 * 8;
    const ushort* gW = W + (size_t)(n0 + wave * 32 + r8) * K + gc8 * 8;
    const int ldso = (wave * 32) * BKK;

    f32x4 acc[4][4] = {};

    // prologue: stage tile 0 into buffer 0 (8 loads, left in flight)
#pragma unroll
    for (int t = 0; t < 4; ++t) {
        gl_lds16(gA + (size_t)t * 8 * K, &As[0][ldso + t * 8 * BKK]);
        gl_lds16(gW + (size_t)t * 8 * K, &Ws[0][ldso + t * 8 * BKK]);
    }

    const int NT = K / BKK;
    for (int kt = 0; kt < NT; ++kt) {
        const int cur = kt & 1;
        if (kt + 1 < NT) {
            const int nxt = cur ^ 1;
            const int k1 = (kt + 1) * BKK;
#pragma unroll
            for (int t = 0; t < 4; ++t) {
                gl_lds16(gA + (size_t)t * 8 * K + k1, &As[nxt][ldso + t * 8 * BKK]);
                gl_lds16(gW + (size_t)t * 8 * K + k1, &Ws[nxt][ldso + t * 8 * BKK]);
            }
            asm volatile("s_waitcnt vmcnt(8)" ::: "memory");
        } else {
            asm volatile("s_waitcnt vmcnt(0)" ::: "memory");
        }
        __builtin_amdgcn_s_barrier();
        __builtin_amdgcn_sched_barrier(0);
#pragma unroll
        for (int kh = 0; kh < 2; ++kh) {
            bf16x8 af[4], bf[4];
            const int co = ((kh * 4 + quad) ^ swf) * 8;
#pragma unroll
            for (int i = 0; i < 4; ++i) {
                af[i] = *(const bf16x8*)&As[cur][(wr * 64 + i * 16 + fr) * BKK + co];
                bf[i] = *(const bf16x8*)&Ws[cur][(wc * 64 + i * 16 + fr) * BKK + co];
            }
#pragma unroll
            for (int i = 0; i < 4; ++i)
#pragma unroll
                for (int j = 0; j < 4; ++j)
                    acc[i][j] = __builtin_amdgcn_mfma_f32_16x16x32_bf16(af[i], bf[j], acc[i][j], 0, 0, 0);
        }
        asm volatile("s_waitcnt lgkmcnt(0)" ::: "memory");
        __builtin_amdgcn_s_barrier();
    }

#pragma unroll
    for (int j = 0; j < 4; ++j) {
        int col = n0 + wc * 64 + j * 16 + fr;
        float bvl = bias[col];
#pragma unroll
        for (int i = 0; i < 4; ++i) {
#pragma unroll
            for (int r = 0; r < 4; ++r) {
                int row = m0 + wr * 64 + i * 16 + quad * 4 + r;
                Cf[(size_t)row * N + col] =
                    acc[i][j][r] + bvl + resid[(size_t)row * N + col];
            }
        }
    }
}

// ---------------------------------------------------------------------------
// MFMA flash attention, S^T formulation, 128 q-rows per block (2 strips per
// wave). K/V LDS double-buffered, one barrier per kb. (Round-5 verified form:
// paired q-tiles (qt, 15-qt), grid 512.)
//  - XCD-aware 1D grid: 8 bx-blocks sharing one (b,h) K/V stream -> same XCD.
//  - raw v_exp_f32 inline asm; v_cvt_pk_bf16_f32 P-pack; setprio(1) on MFMA.
// ---------------------------------------------------------------------------
#define PSP 72
__global__ __launch_bounds__(256, 3) void flash_mfma(
    const ushort* __restrict__ Q, const ushort* __restrict__ K,
    const ushort* __restrict__ VtG, const float* __restrict__ mask,
    ushort* __restrict__ O)
{
    const int id = blockIdx.x;
    const int bx = id >> 6;          // q-tile pair selector 0..7
    const int hb = id & 63;          // xcd = hb % 8 under round-robin
    const int h = hb & 15, b = hb >> 4;
    __shared__ ushort Ks[2][64 * 64];    // [key][d], swizzled 16B chunks
    __shared__ ushort Vt[2][64 * 64];    // [d][key], swizzled 16B chunks
    __shared__ ushort Ps[128 * PSP];     // [q][key], wave-private strips
    const int tid = threadIdx.x;
    const int lane = tid & 63, wave = tid >> 6;
    const int fr = lane & 15, quad = lane >> 4;
    const int srow = tid >> 3;
    const int sc8 = tid & 7;
    const int g8 = sc8 ^ (srow & 7);
    const int swf = fr & 7;

    const ushort* gK0 = K + (size_t)(b * SEQ) * D + h * HD + (size_t)srow * D + g8 * 8;
    const ushort* gK1 = gK0 + (size_t)32 * D;
    const ushort* gV0 = VtG + ((size_t)(b * NH + h) * HD + srow) * SEQ + g8 * 8;
    const ushort* gV1 = gV0 + (size_t)32 * SEQ;
    const float* mrow = mask + (size_t)b * SEQ;
    const float SCALE2 = 0.125f * LOG2E;
    const float MASKC = -10000.0f * LOG2E;

    for (int phase = 0; phase < 2; ++phase) {
        const int qt = phase ? (15 - bx) : bx;      // 128-row q tile
        const int q0 = qt * 128;
        // Q B-fragments for both strips, straight from global
        bf16x8 qf[2][2];
#pragma unroll
        for (int s = 0; s < 2; ++s) {
            const ushort* qptr = Q + ((size_t)(b * SEQ + q0 + s * 64 + wave * 16 + fr)) * D
                                   + h * HD + quad * 8;
            qf[s][0] = *(const bf16x8*)(qptr);
            qf[s][1] = *(const bf16x8*)(qptr + 32);
        }

        f32x4 oacc[2][4] = {};
        float lsum[2][4] = {};
        const int nkb = 2 * qt + 2;

        // prologue: stage kb=0 into buffer 0
        gl_lds16(gK0, &Ks[0][wave * 512]);
        gl_lds16(gK1, &Ks[0][2048 + wave * 512]);
        gl_lds16(gV0, &Vt[0][wave * 512]);
        gl_lds16(gV1, &Vt[0][2048 + wave * 512]);
        __syncthreads();

        for (int kb = 0; kb < nkb; ++kb) {
            const int cur = kb & 1;
            if (kb + 1 < nkb) {
                const int nxt = cur ^ 1;
                gl_lds16(gK0 + (size_t)(kb + 1) * 64 * D, &Ks[nxt][wave * 512]);
                gl_lds16(gK1 + (size_t)(kb + 1) * 64 * D, &Ks[nxt][2048 + wave * 512]);
                gl_lds16(gV0 + (kb + 1) * 64, &Vt[nxt][wave * 512]);
                gl_lds16(gV1 + (kb + 1) * 64, &Vt[nxt][2048 + wave * 512]);
            }
            f32x4 mv[4];
#pragma unroll
            for (int jt = 0; jt < 4; ++jt)
                mv[jt] = ((const f32x4*)(mrow + kb * 64))[jt * 4 + quad];

            const bool s0act = (kb <= 2 * qt);      // strip0 active (wave-uniform)

            // ---- S^T = K·Q^T for both strips (K frags shared) ----
            f32x4 sacc[2][4] = {};
            __builtin_amdgcn_s_setprio(1);
#pragma unroll
            for (int jt = 0; jt < 4; ++jt) {
                const int rb = (jt * 16 + fr) * 64;
                bf16x8 kf0 = *(const bf16x8*)&Ks[cur][rb + ((quad) ^ swf) * 8];
                bf16x8 kf1 = *(const bf16x8*)&Ks[cur][rb + ((4 + quad) ^ swf) * 8];
                sacc[0][jt] = __builtin_amdgcn_mfma_f32_16x16x32_bf16(kf0, qf[0][0], sacc[0][jt], 0, 0, 0);
                sacc[0][jt] = __builtin_amdgcn_mfma_f32_16x16x32_bf16(kf1, qf[0][1], sacc[0][jt], 0, 0, 0);
                sacc[1][jt] = __builtin_amdgcn_mfma_f32_16x16x32_bf16(kf0, qf[1][0], sacc[1][jt], 0, 0, 0);
                sacc[1][jt] = __builtin_amdgcn_mfma_f32_16x16x32_bf16(kf1, qf[1][1], sacc[1][jt], 0, 0, 0);
            }
            __builtin_amdgcn_s_setprio(0);

            // ---- softmax (fixed-max, raw v_exp_f32, cvt_pk bf16 P) ----
            float padd[4][4];
#pragma unroll
            for (int jt = 0; jt < 4; ++jt)
#pragma unroll
                for (int r = 0; r < 4; ++r)
                    padd[jt][r] = fmaf(mv[jt][r], -MASKC, MASKC);
            const int ql = wave * 16 + fr;
#pragma unroll
            for (int s = 0; s < 2; ++s) {
                if (s == 0 && !s0act) continue;
                const bool diag = (kb == 2 * qt + s);
#pragma unroll
                for (int jt = 0; jt < 4; ++jt) {
                    float p[4];
#pragma unroll
                    for (int r = 0; r < 4; ++r) {
                        float v = fmaf(sacc[s][jt][r], SCALE2, padd[jt][r]);
                        if (diag) {
                            int keyl = jt * 16 + quad * 4 + r;
                            v = (keyl > ql) ? -1e30f : v;
                        }
                        float e = exp2_raw(v);
                        p[r] = e;
                        lsum[s][r] += e;
                    }
                    uint w0, w1;
                    asm("v_cvt_pk_bf16_f32 %0, %1, %2" : "=v"(w0) : "v"(p[0]), "v"(p[1]));
                    asm("v_cvt_pk_bf16_f32 %0, %1, %2" : "=v"(w1) : "v"(p[2]), "v"(p[3]));
                    union { uint2 u; ushort4 us; } pu;
                    pu.u.x = w0; pu.u.y = w1;
                    *(ushort4*)&Ps[(s * 64 + wave * 16 + fr) * PSP + jt * 16 + quad * 4] = pu.us;
                }
            }
            // Ps strips are wave-private: no barrier needed.

            // ---- O += P·V (V frags shared across strips) ----
            bf16x8 pa[2][2];
#pragma unroll
            for (int s = 0; s < 2; ++s) {
                pa[s][0] = *(const bf16x8*)&Ps[(s * 64 + wave * 16 + fr) * PSP + quad * 8];
                pa[s][1] = *(const bf16x8*)&Ps[(s * 64 + wave * 16 + fr) * PSP + 32 + quad * 8];
            }
            __builtin_amdgcn_s_setprio(1);
#pragma unroll
            for (int dt = 0; dt < 4; ++dt) {
                const int rb = (dt * 16 + fr) * 64;
                bf16x8 vf0 = *(const bf16x8*)&Vt[cur][rb + ((quad) ^ swf) * 8];
                bf16x8 vf1 = *(const bf16x8*)&Vt[cur][rb + ((4 + quad) ^ swf) * 8];
                if (s0act) {
                    oacc[0][dt] = __builtin_amdgcn_mfma_f32_16x16x32_bf16(pa[0][0], vf0, oacc[0][dt], 0, 0, 0);
                    oacc[0][dt] = __builtin_amdgcn_mfma_f32_16x16x32_bf16(pa[0][1], vf1, oacc[0][dt], 0, 0, 0);
                }
                oacc[1][dt] = __builtin_amdgcn_mfma_f32_16x16x32_bf16(pa[1][0], vf0, oacc[1][dt], 0, 0, 0);
                oacc[1][dt] = __builtin_amdgcn_mfma_f32_16x16x32_bf16(pa[1][1], vf1, oacc[1][dt], 0, 0, 0);
            }
            __builtin_amdgcn_s_setprio(0);
            __syncthreads();   // drains prefetch vmcnt + all LDS reads of buf[cur]
        }

        // ---- finalize both strips ----
#pragma unroll
        for (int s = 0; s < 2; ++s) {
            float lt = (lsum[s][0] + lsum[s][1]) + (lsum[s][2] + lsum[s][3]);
            lt += __shfl_xor(lt, 16, 64);
            lt += __shfl_xor(lt, 32, 64);
            float linv[4];
#pragma unroll
            for (int r = 0; r < 4; ++r)
                linv[r] = 1.0f / __shfl(lt, quad * 4 + r, 64);
#pragma unroll
            for (int dt = 0; dt < 4; ++dt)
#pragma unroll
                for (int r = 0; r < 4; ++r) {
                    int q = q0 + s * 64 + wave * 16 + quad * 4 + r;
                    O[((size_t)(b * SEQ + q)) * D + h * HD + dt * 16 + fr] =
                        f2bf(oacc[s][dt][r] * linv[r]);
                }
        }
    }
}

// ---------------------------------------------------------------------------
extern "C" void kernel_launch(void* const* d_in, const int* in_sizes, int n_in,
                              void* d_out, int out_size, void* d_ws, size_t ws_size,
                              hipStream_t stream)
{
    const float* x     = (const float*)d_in[0];
    const float* amask = (const float*)d_in[1];
    const float* Wq    = (const float*)d_in[2];
    const float* bq    = (const float*)d_in[3];
    const float* Wk    = (const float*)d_in[4];
    const float* bk    = (const float*)d_in[5];
    const float* Wv    = (const float*)d_in[6];
    const float* bv    = (const float*)d_in[7];
    const float* Wo    = (const float*)d_in[8];
    const float* bo    = (const float*)d_in[9];
    const float* gamma = (const float*)d_in[10];
    const float* beta  = (const float*)d_in[11];
    float* out = (float*)d_out;

    const size_t MROWS = (size_t)BATCH * SEQ;  // 8192
    const size_t MB = 1024 * 1024;
    char* ws = (char*)d_ws;
    ushort* Qb    = (ushort*)(ws);             // 16 MB bf16 [B,S,D]
    ushort* Kb    = (ushort*)(ws + 16 * MB);   // 16 MB [B,S,D]
    ushort* Vtb   = (ushort*)(ws + 32 * MB);   // 16 MB [B,H,D,S]
    ushort* xn_bf = (ushort*)(ws + 48 * MB);   // 16 MB (reused as attn_bf)
    ushort* Wq_bf = (ushort*)(ws + 64 * MB);   // Wq,Wk,Wv,Wo contiguous
    ushort* Wo_bf = (ushort*)(ws + 70 * MB);
    ushort* attn_bf = xn_bf;

    // fused LN + weight-convert: 8192 LN blocks + 4096 cvt blocks
    prep<<<dim3((unsigned)(MROWS + 4096)), 256, 0, stream>>>(
        x, gamma, beta, xn_bf, Wq, Wk, Wv, Wo, Wq_bf);

    gemm_qkv<<<dim3(24, 64), 256, 0, stream>>>(xn_bf, Wq_bf, bq, bk, bv,
                                               Qb, Kb, Vtb, (int)MROWS, D);

    flash_mfma<<<dim3(512), 256, 0, stream>>>(Qb, Kb, Vtb, amask, attn_bf);

    gemm_out<<<dim3(8, 64), 256, 0, stream>>>(attn_bf, Wo_bf, bo, x, out,
                                              (int)MROWS, D, D);
}

// Round 9
// 279.363 us; speedup vs baseline: 1.0255x; 1.0119x over previous
//
#include <hip/hip_runtime.h>

#define D 1024
#define NH 16
#define HD 64
#define SEQ 2048
#define BATCH 4
#define LN_EPS 1e-5f
#define LOG2E 1.44269504088896f

typedef __attribute__((ext_vector_type(8))) __bf16 bf16x8;
typedef __attribute__((ext_vector_type(4))) float f32x4;

__device__ __forceinline__ ushort f2bf(float f) {
    union { float f; uint u; } c; c.f = f;
    uint u = c.u + 0x7fffu + ((c.u >> 16) & 1u);   // RNE
    return (ushort)(u >> 16);
}

// async global->LDS DMA, 16B per lane; LDS dest = wave-uniform base + lane*16
__device__ __forceinline__ void gl_lds16(const ushort* g, ushort* lds) {
    __builtin_amdgcn_global_load_lds(
        (const __attribute__((address_space(1))) void*)g,
        (__attribute__((address_space(3))) void*)lds, 16, 0, 0);
}

// raw v_exp_f32: D = 2^S0 (cdna4_isa §3). Single VALU inst, no OCML path.
__device__ __forceinline__ float exp2_raw(float v) {
    float e;
    asm("v_exp_f32 %0, %1" : "=v"(e) : "v"(v));
    return e;
}

// ---------------------------------------------------------------------------
// prep: fused {LayerNorm rows} + {fp32->bf16 convert of 4 weight matrices}.
// Blocks [0, 8192)      : LN, one row each (256 thr x float4), writes bf16.
// Blocks [8192, 12288)  : weight convert, 1024 floats per block.
// ---------------------------------------------------------------------------
__global__ __launch_bounds__(256) void prep(
    const float* __restrict__ x, const float* __restrict__ gamma,
    const float* __restrict__ beta, ushort* __restrict__ xn,
    const float* __restrict__ w0, const float* __restrict__ w1,
    const float* __restrict__ w2, const float* __restrict__ w3,
    ushort* __restrict__ wout)
{
    const int bid = blockIdx.x;
    const int tid = threadIdx.x;
    if (bid < BATCH * SEQ) {
        // ---- LayerNorm ----
        int row = bid;
        float4 v = ((const float4*)(x + (size_t)row * D))[tid];
        float s = v.x + v.y + v.z + v.w;
#pragma unroll
        for (int off = 32; off > 0; off >>= 1) s += __shfl_down(s, off, 64);
        __shared__ float red1[4], red2[4];
        int wid = tid >> 6, lane = tid & 63;
        if (lane == 0) red1[wid] = s;
        __syncthreads();
        float mean = (red1[0] + red1[1] + red1[2] + red1[3]) * (1.0f / D);
        float dx = v.x - mean, dy = v.y - mean, dz = v.z - mean, dw = v.w - mean;
        float ss = dx * dx + dy * dy + dz * dz + dw * dw;
#pragma unroll
        for (int off = 32; off > 0; off >>= 1) ss += __shfl_down(ss, off, 64);
        if (lane == 0) red2[wid] = ss;
        __syncthreads();
        float var = (red2[0] + red2[1] + red2[2] + red2[3]) * (1.0f / D);
        float rstd = rsqrtf(var + LN_EPS);
        float4 g = ((const float4*)gamma)[tid];
        float4 b = ((const float4*)beta)[tid];
        ushort4 o;
        o.x = f2bf(dx * rstd * g.x + b.x);
        o.y = f2bf(dy * rstd * g.y + b.y);
        o.z = f2bf(dz * rstd * g.z + b.z);
        o.w = f2bf(dw * rstd * g.w + b.w);
        ((ushort4*)(xn + (size_t)row * D))[tid] = o;
    } else {
        // ---- weight convert ----
        const int n = D * D;
        int p = bid - BATCH * SEQ;
        int sel = p >> 10;                 // 0..3
        int xblk = p & 1023;
        const float* in = sel == 0 ? w0 : (sel == 1 ? w1 : (sel == 2 ? w2 : w3));
        int i = (xblk * 256 + tid) * 4;
        float4 v = *(const float4*)(in + i);
        ushort4 o;
        o.x = f2bf(v.x); o.y = f2bf(v.y); o.z = f2bf(v.z); o.w = f2bf(v.w);
        *(ushort4*)(wout + (size_t)sel * n + i) = o;
    }
}

// ---------------------------------------------------------------------------
// GEMM (final form): 128x128 tile, BK=64, XOR-swizzled DMA staging, 2-phase
// double-buffer with a single compiler-scheduled __syncthreads per K-step.
// SESSION VERDICT on alternatives (all measured, all regressed):
//   - 256^2 coarse 2-phase + counted vmcnt: 115.6us (1 blk/CU, 1.5-round
//     tail, V-scatter write burst 52->82MB).
//   - BK=32 (5 blk/CU theoretical): 94.7us (2x barrier count; real residency
//     scheduler-limited — Occupancy rose 16.5->26 but MfmaUtil FELL).
//   - counted vmcnt(8) + 2 raw barriers at 128^2: 94.7us (sched_barrier(0)
//     defeats hipcc's fine lgkmcnt ds_read<->MFMA interleave).
// This structure (89.5us, MfmaUtil 23.5) is the 2-phase ceiling for this
// shape; past it requires the full 8-phase ledger (failed to derive safely;
// catalog marks 128^2+8ph OPEN, and 256^2 is geometry-blocked by the tail).
// ---------------------------------------------------------------------------
#define BM 128
#define BKK 64

// ---------------------------------------------------------------------------
// Fused QKV GEMM: W = stacked [Wq;Wk;Wv] = [3072][1024] bf16. Grid (24, 64).
// Region 0->Q, 1->K row-major bf16; region 2 -> V transposed to [B,H,D,S].
// ---------------------------------------------------------------------------
__global__ __launch_bounds__(256) void gemm_qkv(
    const ushort* __restrict__ A,    // [M,1024] bf16
    const ushort* __restrict__ W,    // [3072,1024] bf16
    const float* __restrict__ bq, const float* __restrict__ bk,
    const float* __restrict__ bv,
    ushort* __restrict__ Cq, ushort* __restrict__ Ck,
    ushort* __restrict__ CvT,
    int M, int K)
{
    __shared__ ushort As[2][BM * BKK];   // 2 x 16 KB
    __shared__ ushort Ws[2][BM * BKK];
    const int tid = threadIdx.x;
    const int lane = tid & 63;
    const int wave = tid >> 6;
    const int wr = wave >> 1, wc = wave & 1;
    const int m0 = blockIdx.y * BM;
    const int n0g = blockIdx.x * BM;
    const int region = n0g >> 10;
    const int n0l = n0g & 1023;
    const float* bias = region == 0 ? bq : (region == 1 ? bk : bv);
    const int fr = lane & 15, quad = lane >> 4;
    const int r8 = lane >> 3, c8 = lane & 7;
    const int gc8 = c8 ^ r8;               // swizzled global chunk
    const int swf = fr & 7;

    const ushort* gA = A + (size_t)(m0 + wave * 32 + r8) * K + gc8 * 8;
    const ushort* gW = W + (size_t)(n0g + wave * 32 + r8) * K + gc8 * 8;
    const int ldso = (wave * 32) * BKK;

    f32x4 acc[4][4] = {};

    // prologue: stage tile 0 into buffer 0
#pragma unroll
    for (int t = 0; t < 4; ++t) {
        gl_lds16(gA + (size_t)t * 8 * K, &As[0][ldso + t * 8 * BKK]);
        gl_lds16(gW + (size_t)t * 8 * K, &Ws[0][ldso + t * 8 * BKK]);
    }
    __syncthreads();

    for (int k0 = 0; k0 < K; k0 += BKK) {
        const int cur = (k0 >> 6) & 1;
        if (k0 + BKK < K) {
            const int nxt = cur ^ 1;
#pragma unroll
            for (int t = 0; t < 4; ++t) {
                gl_lds16(gA + (size_t)t * 8 * K + k0 + BKK, &As[nxt][ldso + t * 8 * BKK]);
                gl_lds16(gW + (size_t)t * 8 * K + k0 + BKK, &Ws[nxt][ldso + t * 8 * BKK]);
            }
        }
#pragma unroll
        for (int kh = 0; kh < 2; ++kh) {
            bf16x8 af[4], bf[4];
            const int co = ((kh * 4 + quad) ^ swf) * 8;
#pragma unroll
            for (int i = 0; i < 4; ++i) {
                af[i] = *(const bf16x8*)&As[cur][(wr * 64 + i * 16 + fr) * BKK + co];
                bf[i] = *(const bf16x8*)&Ws[cur][(wc * 64 + i * 16 + fr) * BKK + co];
            }
#pragma unroll
            for (int i = 0; i < 4; ++i)
#pragma unroll
                for (int j = 0; j < 4; ++j)
                    acc[i][j] = __builtin_amdgcn_mfma_f32_16x16x32_bf16(af[i], bf[j], acc[i][j], 0, 0, 0);
        }
        __syncthreads();   // drains prefetch vmcnt + fragment lgkm; one barrier/K-step
    }

#pragma unroll
    for (int j = 0; j < 4; ++j) {
        int col = n0l + wc * 64 + j * 16 + fr;
        float bvl = bias[col];
#pragma unroll
        for (int i = 0; i < 4; ++i) {
#pragma unroll
            for (int r = 0; r < 4; ++r) {
                int row = m0 + wr * 64 + i * 16 + quad * 4 + r;
                ushort hv = f2bf(acc[i][j][r] + bvl);
                if (region == 0) {
                    Cq[(size_t)row * 1024 + col] = hv;
                } else if (region == 1) {
                    Ck[(size_t)row * 1024 + col] = hv;
                } else {
                    int bb = row >> 11, s = row & 2047;
                    int hh = col >> 6, d = col & 63;
                    CvT[(((size_t)bb * NH + hh) * HD + d) * SEQ + s] = hv;
                }
            }
        }
    }
}

// ---------------------------------------------------------------------------
// Output projection GEMM (+bias +fp32 residual), same BK=64 dbuf structure.
// ---------------------------------------------------------------------------
__global__ __launch_bounds__(256) void gemm_out(
    const ushort* __restrict__ A, const ushort* __restrict__ W,
    const float* __restrict__ bias, const float* __restrict__ resid,
    float* __restrict__ Cf, int M, int N, int K)
{
    __shared__ ushort As[2][BM * BKK];
    __shared__ ushort Ws[2][BM * BKK];
    const int tid = threadIdx.x;
    const int lane = tid & 63;
    const int wave = tid >> 6;
    const int wr = wave >> 1, wc = wave & 1;
    const int m0 = blockIdx.y * BM, n0 = blockIdx.x * BM;
    const int fr = lane & 15, quad = lane >> 4;
    const int r8 = lane >> 3, c8 = lane & 7;
    const int gc8 = c8 ^ r8;
    const int swf = fr & 7;

    const ushort* gA = A + (size_t)(m0 + wave * 32 + r8) * K + gc8 * 8;
    const ushort* gW = W + (size_t)(n0 + wave * 32 + r8) * K + gc8 * 8;
    const int ldso = (wave * 32) * BKK;

    f32x4 acc[4][4] = {};

    // prologue: stage tile 0 into buffer 0
#pragma unroll
    for (int t = 0; t < 4; ++t) {
        gl_lds16(gA + (size_t)t * 8 * K, &As[0][ldso + t * 8 * BKK]);
        gl_lds16(gW + (size_t)t * 8 * K, &Ws[0][ldso + t * 8 * BKK]);
    }
    __syncthreads();

    for (int k0 = 0; k0 < K; k0 += BKK) {
        const int cur = (k0 >> 6) & 1;
        if (k0 + BKK < K) {
            const int nxt = cur ^ 1;
#pragma unroll
            for (int t = 0; t < 4; ++t) {
                gl_lds16(gA + (size_t)t * 8 * K + k0 + BKK, &As[nxt][ldso + t * 8 * BKK]);
                gl_lds16(gW + (size_t)t * 8 * K + k0 + BKK, &Ws[nxt][ldso + t * 8 * BKK]);
            }
        }
#pragma unroll
        for (int kh = 0; kh < 2; ++kh) {
            bf16x8 af[4], bf[4];
            const int co = ((kh * 4 + quad) ^ swf) * 8;
#pragma unroll
            for (int i = 0; i < 4; ++i) {
                af[i] = *(const bf16x8*)&As[cur][(wr * 64 + i * 16 + fr) * BKK + co];
                bf[i] = *(const bf16x8*)&Ws[cur][(wc * 64 + i * 16 + fr) * BKK + co];
            }
#pragma unroll
            for (int i = 0; i < 4; ++i)
#pragma unroll
                for (int j = 0; j < 4; ++j)
                    acc[i][j] = __builtin_amdgcn_mfma_f32_16x16x32_bf16(af[i], bf[j], acc[i][j], 0, 0, 0);
        }
        __syncthreads();
    }

#pragma unroll
    for (int j = 0; j < 4; ++j) {
        int col = n0 + wc * 64 + j * 16 + fr;
        float bvl = bias[col];
#pragma unroll
        for (int i = 0; i < 4; ++i) {
#pragma unroll
            for (int r = 0; r < 4; ++r) {
                int row = m0 + wr * 64 + i * 16 + quad * 4 + r;
                Cf[(size_t)row * N + col] =
                    acc[i][j][r] + bvl + resid[(size_t)row * N + col];
            }
        }
    }
}

// ---------------------------------------------------------------------------
// MFMA flash attention, S^T formulation, 128 q-rows per block (2 strips per
// wave). K/V LDS double-buffered, one barrier per kb. Paired q-tiles
// (qt, 15-qt) per block: uniform 34 iters (grid split to 1024 regressed).
//  - XCD-aware 1D grid: 8 bx-blocks sharing one (b,h) K/V stream -> same XCD.
//  - raw v_exp_f32 inline asm; v_cvt_pk_bf16_f32 P-pack; setprio(1) on MFMA.
// ---------------------------------------------------------------------------
#define PSP 72
__global__ __launch_bounds__(256, 3) void flash_mfma(
    const ushort* __restrict__ Q, const ushort* __restrict__ K,
    const ushort* __restrict__ VtG, const float* __restrict__ mask,
    ushort* __restrict__ O)
{
    const int id = blockIdx.x;
    const int bx = id >> 6;          // q-tile pair selector 0..7
    const int hb = id & 63;          // xcd = hb % 8 under round-robin
    const int h = hb & 15, b = hb >> 4;
    __shared__ ushort Ks[2][64 * 64];    // [key][d], swizzled 16B chunks
    __shared__ ushort Vt[2][64 * 64];    // [d][key], swizzled 16B chunks
    __shared__ ushort Ps[128 * PSP];     // [q][key], wave-private strips
    const int tid = threadIdx.x;
    const int lane = tid & 63, wave = tid >> 6;
    const int fr = lane & 15, quad = lane >> 4;
    const int srow = tid >> 3;
    const int sc8 = tid & 7;
    const int g8 = sc8 ^ (srow & 7);
    const int swf = fr & 7;

    const ushort* gK0 = K + (size_t)(b * SEQ) * D + h * HD + (size_t)srow * D + g8 * 8;
    const ushort* gK1 = gK0 + (size_t)32 * D;
    const ushort* gV0 = VtG + ((size_t)(b * NH + h) * HD + srow) * SEQ + g8 * 8;
    const ushort* gV1 = gV0 + (size_t)32 * SEQ;
    const float* mrow = mask + (size_t)b * SEQ;
    const float SCALE2 = 0.125f * LOG2E;
    const float MASKC = -10000.0f * LOG2E;

    for (int phase = 0; phase < 2; ++phase) {
        const int qt = phase ? (15 - bx) : bx;      // 128-row q tile
        const int q0 = qt * 128;
        // Q B-fragments for both strips, straight from global
        bf16x8 qf[2][2];
#pragma unroll
        for (int s = 0; s < 2; ++s) {
            const ushort* qptr = Q + ((size_t)(b * SEQ + q0 + s * 64 + wave * 16 + fr)) * D
                                   + h * HD + quad * 8;
            qf[s][0] = *(const bf16x8*)(qptr);
            qf[s][1] = *(const bf16x8*)(qptr + 32);
        }

        f32x4 oacc[2][4] = {};
        float lsum[2][4] = {};
        const int nkb = 2 * qt + 2;

        // prologue: stage kb=0 into buffer 0
        gl_lds16(gK0, &Ks[0][wave * 512]);
        gl_lds16(gK1, &Ks[0][2048 + wave * 512]);
        gl_lds16(gV0, &Vt[0][wave * 512]);
        gl_lds16(gV1, &Vt[0][2048 + wave * 512]);
        __syncthreads();

        for (int kb = 0; kb < nkb; ++kb) {
            const int cur = kb & 1;
            if (kb + 1 < nkb) {
                const int nxt = cur ^ 1;
                gl_lds16(gK0 + (size_t)(kb + 1) * 64 * D, &Ks[nxt][wave * 512]);
                gl_lds16(gK1 + (size_t)(kb + 1) * 64 * D, &Ks[nxt][2048 + wave * 512]);
                gl_lds16(gV0 + (kb + 1) * 64, &Vt[nxt][wave * 512]);
                gl_lds16(gV1 + (kb + 1) * 64, &Vt[nxt][2048 + wave * 512]);
            }
            f32x4 mv[4];
#pragma unroll
            for (int jt = 0; jt < 4; ++jt)
                mv[jt] = ((const f32x4*)(mrow + kb * 64))[jt * 4 + quad];

            const bool s0act = (kb <= 2 * qt);      // strip0 active (wave-uniform)

            // ---- S^T = K·Q^T for both strips (K frags shared) ----
            f32x4 sacc[2][4] = {};
            __builtin_amdgcn_s_setprio(1);
#pragma unroll
            for (int jt = 0; jt < 4; ++jt) {
                const int rb = (jt * 16 + fr) * 64;
                bf16x8 kf0 = *(const bf16x8*)&Ks[cur][rb + ((quad) ^ swf) * 8];
                bf16x8 kf1 = *(const bf16x8*)&Ks[cur][rb + ((4 + quad) ^ swf) * 8];
                sacc[0][jt] = __builtin_amdgcn_mfma_f32_16x16x32_bf16(kf0, qf[0][0], sacc[0][jt], 0, 0, 0);
                sacc[0][jt] = __builtin_amdgcn_mfma_f32_16x16x32_bf16(kf1, qf[0][1], sacc[0][jt], 0, 0, 0);
                sacc[1][jt] = __builtin_amdgcn_mfma_f32_16x16x32_bf16(kf0, qf[1][0], sacc[1][jt], 0, 0, 0);
                sacc[1][jt] = __builtin_amdgcn_mfma_f32_16x16x32_bf16(kf1, qf[1][1], sacc[1][jt], 0, 0, 0);
            }
            __builtin_amdgcn_s_setprio(0);

            // ---- softmax (fixed-max, raw v_exp_f32, cvt_pk bf16 P) ----
            float padd[4][4];
#pragma unroll
            for (int jt = 0; jt < 4; ++jt)
#pragma unroll
                for (int r = 0; r < 4; ++r)
                    padd[jt][r] = fmaf(mv[jt][r], -MASKC, MASKC);
            const int ql = wave * 16 + fr;
#pragma unroll
            for (int s = 0; s < 2; ++s) {
                if (s == 0 && !s0act) continue;
                const bool diag = (kb == 2 * qt + s);
#pragma unroll
                for (int jt = 0; jt < 4; ++jt) {
                    float p[4];
#pragma unroll
                    for (int r = 0; r < 4; ++r) {
                        float v = fmaf(sacc[s][jt][r], SCALE2, padd[jt][r]);
                        if (diag) {
                            int keyl = jt * 16 + quad * 4 + r;
                            v = (keyl > ql) ? -1e30f : v;
                        }
                        float e = exp2_raw(v);
                        p[r] = e;
                        lsum[s][r] += e;
                    }
                    uint w0, w1;
                    asm("v_cvt_pk_bf16_f32 %0, %1, %2" : "=v"(w0) : "v"(p[0]), "v"(p[1]));
                    asm("v_cvt_pk_bf16_f32 %0, %1, %2" : "=v"(w1) : "v"(p[2]), "v"(p[3]));
                    union { uint2 u; ushort4 us; } pu;
                    pu.u.x = w0; pu.u.y = w1;
                    *(ushort4*)&Ps[(s * 64 + wave * 16 + fr) * PSP + jt * 16 + quad * 4] = pu.us;
                }
            }
            // Ps strips are wave-private: no barrier needed.

            // ---- O += P·V (V frags shared across strips) ----
            bf16x8 pa[2][2];
#pragma unroll
            for (int s = 0; s < 2; ++s) {
                pa[s][0] = *(const bf16x8*)&Ps[(s * 64 + wave * 16 + fr) * PSP + quad * 8];
                pa[s][1] = *(const bf16x8*)&Ps[(s * 64 + wave * 16 + fr) * PSP + 32 + quad * 8];
            }
            __builtin_amdgcn_s_setprio(1);
#pragma unroll
            for (int dt = 0; dt < 4; ++dt) {
                const int rb = (dt * 16 + fr) * 64;
                bf16x8 vf0 = *(const bf16x8*)&Vt[cur][rb + ((quad) ^ swf) * 8];
                bf16x8 vf1 = *(const bf16x8*)&Vt[cur][rb + ((4 + quad) ^ swf) * 8];
                if (s0act) {
                    oacc[0][dt] = __builtin_amdgcn_mfma_f32_16x16x32_bf16(pa[0][0], vf0, oacc[0][dt], 0, 0, 0);
                    oacc[0][dt] = __builtin_amdgcn_mfma_f32_16x16x32_bf16(pa[0][1], vf1, oacc[0][dt], 0, 0, 0);
                }
                oacc[1][dt] = __builtin_amdgcn_mfma_f32_16x16x32_bf16(pa[1][0], vf0, oacc[1][dt], 0, 0, 0);
                oacc[1][dt] = __builtin_amdgcn_mfma_f32_16x16x32_bf16(pa[1][1], vf1, oacc[1][dt], 0, 0, 0);
            }
            __builtin_amdgcn_s_setprio(0);
            __syncthreads();   // drains prefetch vmcnt + all LDS reads of buf[cur]
        }

        // ---- finalize both strips ----
#pragma unroll
        for (int s = 0; s < 2; ++s) {
            float lt = (lsum[s][0] + lsum[s][1]) + (lsum[s][2] + lsum[s][3]);
            lt += __shfl_xor(lt, 16, 64);
            lt += __shfl_xor(lt, 32, 64);
            float linv[4];
#pragma unroll
            for (int r = 0; r < 4; ++r)
                linv[r] = 1.0f / __shfl(lt, quad * 4 + r, 64);
#pragma unroll
            for (int dt = 0; dt < 4; ++dt)
#pragma unroll
                for (int r = 0; r < 4; ++r) {
                    int q = q0 + s * 64 + wave * 16 + quad * 4 + r;
                    O[((size_t)(b * SEQ + q)) * D + h * HD + dt * 16 + fr] =
                        f2bf(oacc[s][dt][r] * linv[r]);
                }
        }
    }
}

// ---------------------------------------------------------------------------
extern "C" void kernel_launch(void* const* d_in, const int* in_sizes, int n_in,
                              void* d_out, int out_size, void* d_ws, size_t ws_size,
                              hipStream_t stream)
{
    const float* x     = (const float*)d_in[0];
    const float* amask = (const float*)d_in[1];
    const float* Wq    = (const float*)d_in[2];
    const float* bq    = (const float*)d_in[3];
    const float* Wk    = (const float*)d_in[4];
    const float* bk    = (const float*)d_in[5];
    const float* Wv    = (const float*)d_in[6];
    const float* bv    = (const float*)d_in[7];
    const float* Wo    = (const float*)d_in[8];
    const float* bo    = (const float*)d_in[9];
    const float* gamma = (const float*)d_in[10];
    const float* beta  = (const float*)d_in[11];
    float* out = (float*)d_out;

    const size_t MROWS = (size_t)BATCH * SEQ;  // 8192
    const size_t MB = 1024 * 1024;
    char* ws = (char*)d_ws;
    ushort* Qb    = (ushort*)(ws);             // 16 MB bf16 [B,S,D]
    ushort* Kb    = (ushort*)(ws + 16 * MB);   // 16 MB [B,S,D]
    ushort* Vtb   = (ushort*)(ws + 32 * MB);   // 16 MB [B,H,D,S]
    ushort* xn_bf = (ushort*)(ws + 48 * MB);   // 16 MB (reused as attn_bf)
    ushort* Wq_bf = (ushort*)(ws + 64 * MB);   // Wq,Wk,Wv,Wo contiguous
    ushort* Wo_bf = (ushort*)(ws + 70 * MB);
    ushort* attn_bf = xn_bf;

    // fused LN + weight-convert: 8192 LN blocks + 4096 cvt blocks
    prep<<<dim3((unsigned)(MROWS + 4096)), 256, 0, stream>>>(
        x, gamma, beta, xn_bf, Wq, Wk, Wv, Wo, Wq_bf);

    gemm_qkv<<<dim3(24, 64), 256, 0, stream>>>(xn_bf, Wq_bf, bq, bk, bv,
                                               Qb, Kb, Vtb, (int)MROWS, D);

    flash_mfma<<<dim3(512), 256, 0, stream>>>(Qb, Kb, Vtb, amask, attn_bf);

    gemm_out<<<dim3(8, 64), 256, 0, stream>>>(attn_bf, Wo_bf, bo, x, out,
                                              (int)MROWS, D, D);
}

// Round 10
// 272.995 us; speedup vs baseline: 1.0494x; 1.0233x over previous
//
#include <hip/hip_runtime.h>

#define D 1024
#define NH 16
#define HD 64
#define SEQ 2048
#define BATCH 4
#define LN_EPS 1e-5f
#define LOG2E 1.44269504088896f

typedef __attribute__((ext_vector_type(8))) __bf16 bf16x8;
typedef __attribute__((ext_vector_type(4))) float f32x4;

__device__ __forceinline__ ushort f2bf(float f) {
    union { float f; uint u; } c; c.f = f;
    uint u = c.u + 0x7fffu + ((c.u >> 16) & 1u);   // RNE
    return (ushort)(u >> 16);
}

// async global->LDS DMA, 16B per lane; LDS dest = wave-uniform base + lane*16
__device__ __forceinline__ void gl_lds16(const ushort* g, ushort* lds) {
    __builtin_amdgcn_global_load_lds(
        (const __attribute__((address_space(1))) void*)g,
        (__attribute__((address_space(3))) void*)lds, 16, 0, 0);
}

// raw v_exp_f32: D = 2^S0 (cdna4_isa §3). Single VALU inst, no OCML path.
__device__ __forceinline__ float exp2_raw(float v) {
    float e;
    asm("v_exp_f32 %0, %1" : "=v"(e) : "v"(v));
    return e;
}

// ---------------------------------------------------------------------------
// prep: fused {LayerNorm rows} + {fp32->bf16 convert of 4 weight matrices}.
// Round 10: LN = ONE WAVE PER ROW (4 rows/block), pure shfl_xor butterfly
// reduction — zero barriers, zero LDS (was 4 waves/row + 2 syncthreads + LDS
// round-trips). Blocks [0, 2048): LN, 4 rows each. [2048, 6144): cvt.
// ---------------------------------------------------------------------------
__global__ __launch_bounds__(256) void prep(
    const float* __restrict__ x, const float* __restrict__ gamma,
    const float* __restrict__ beta, ushort* __restrict__ xn,
    const float* __restrict__ w0, const float* __restrict__ w1,
    const float* __restrict__ w2, const float* __restrict__ w3,
    ushort* __restrict__ wout)
{
    const int bid = blockIdx.x;
    const int tid = threadIdx.x;
    if (bid < BATCH * SEQ / 4) {
        // ---- LayerNorm: one row per wave ----
        const int wave = tid >> 6, lane = tid & 63;
        const int row = bid * 4 + wave;
        const float4* xr = (const float4*)(x + (size_t)row * D);
        float4 v[4];
        float s = 0.f;
#pragma unroll
        for (int t = 0; t < 4; ++t) {
            v[t] = xr[t * 64 + lane];
            s += (v[t].x + v[t].y) + (v[t].z + v[t].w);
        }
#pragma unroll
        for (int off = 32; off > 0; off >>= 1) s += __shfl_xor(s, off, 64);
        float mean = s * (1.0f / D);
        float ss = 0.f;
#pragma unroll
        for (int t = 0; t < 4; ++t) {
            float dx = v[t].x - mean, dy = v[t].y - mean;
            float dz = v[t].z - mean, dw = v[t].w - mean;
            ss += (dx * dx + dy * dy) + (dz * dz + dw * dw);
        }
#pragma unroll
        for (int off = 32; off > 0; off >>= 1) ss += __shfl_xor(ss, off, 64);
        float rstd = rsqrtf(ss * (1.0f / D) + LN_EPS);
        ushort4* xo = (ushort4*)(xn + (size_t)row * D);
#pragma unroll
        for (int t = 0; t < 4; ++t) {
            float4 g = ((const float4*)gamma)[t * 64 + lane];
            float4 b = ((const float4*)beta)[t * 64 + lane];
            ushort4 o;
            o.x = f2bf((v[t].x - mean) * rstd * g.x + b.x);
            o.y = f2bf((v[t].y - mean) * rstd * g.y + b.y);
            o.z = f2bf((v[t].z - mean) * rstd * g.z + b.z);
            o.w = f2bf((v[t].w - mean) * rstd * g.w + b.w);
            xo[t * 64 + lane] = o;
        }
    } else {
        // ---- weight convert ----
        const int n = D * D;
        int p = bid - BATCH * SEQ / 4;
        int sel = p >> 10;                 // 0..3
        int xblk = p & 1023;
        const float* in = sel == 0 ? w0 : (sel == 1 ? w1 : (sel == 2 ? w2 : w3));
        int i = (xblk * 256 + tid) * 4;
        float4 v = *(const float4*)(in + i);
        ushort4 o;
        o.x = f2bf(v.x); o.y = f2bf(v.y); o.z = f2bf(v.z); o.w = f2bf(v.w);
        *(ushort4*)(wout + (size_t)sel * n + i) = o;
    }
}

// ---------------------------------------------------------------------------
// GEMM (final form): 128x128 tile, BK=64, XOR-swizzled DMA staging, 2-phase
// double-buffer with a single compiler-scheduled __syncthreads per K-step.
// SESSION VERDICT on alternatives (all measured, all regressed):
//   - 256^2 coarse 2-phase + counted vmcnt: 115.6us (1 blk/CU, 1.5-round
//     tail, V-scatter write burst 52->82MB).
//   - BK=32 (5 blk/CU theoretical): 94.7us (2x barrier count; real residency
//     scheduler-limited — Occupancy rose 16.5->26 but MfmaUtil FELL).
//   - counted vmcnt(8) + 2 raw barriers at 128^2: 94.7us (consistent with
//     catalog regime-gate: T4 counted-vmcnt is null/negative without the
//     full T3 8-phase interleave).
// This structure (89.5us, MfmaUtil 23.5) is the 2-phase ceiling for this
// shape; past it requires the full 8-phase ledger (not safely derivable here).
// ---------------------------------------------------------------------------
#define BM 128
#define BKK 64

// ---------------------------------------------------------------------------
// Fused QKV GEMM: W = stacked [Wq;Wk;Wv] = [3072][1024] bf16. Grid (24, 64).
// Region 0->Q, 1->K row-major bf16; region 2 -> V transposed to [B,H,D,S].
// ---------------------------------------------------------------------------
__global__ __launch_bounds__(256) void gemm_qkv(
    const ushort* __restrict__ A,    // [M,1024] bf16
    const ushort* __restrict__ W,    // [3072,1024] bf16
    const float* __restrict__ bq, const float* __restrict__ bk,
    const float* __restrict__ bv,
    ushort* __restrict__ Cq, ushort* __restrict__ Ck,
    ushort* __restrict__ CvT,
    int M, int K)
{
    __shared__ ushort As[2][BM * BKK];   // 2 x 16 KB
    __shared__ ushort Ws[2][BM * BKK];
    const int tid = threadIdx.x;
    const int lane = tid & 63;
    const int wave = tid >> 6;
    const int wr = wave >> 1, wc = wave & 1;
    const int m0 = blockIdx.y * BM;
    const int n0g = blockIdx.x * BM;
    const int region = n0g >> 10;
    const int n0l = n0g & 1023;
    const float* bias = region == 0 ? bq : (region == 1 ? bk : bv);
    const int fr = lane & 15, quad = lane >> 4;
    const int r8 = lane >> 3, c8 = lane & 7;
    const int gc8 = c8 ^ r8;               // swizzled global chunk
    const int swf = fr & 7;

    const ushort* gA = A + (size_t)(m0 + wave * 32 + r8) * K + gc8 * 8;
    const ushort* gW = W + (size_t)(n0g + wave * 32 + r8) * K + gc8 * 8;
    const int ldso = (wave * 32) * BKK;

    f32x4 acc[4][4] = {};

    // prologue: stage tile 0 into buffer 0
#pragma unroll
    for (int t = 0; t < 4; ++t) {
        gl_lds16(gA + (size_t)t * 8 * K, &As[0][ldso + t * 8 * BKK]);
        gl_lds16(gW + (size_t)t * 8 * K, &Ws[0][ldso + t * 8 * BKK]);
    }
    __syncthreads();

    for (int k0 = 0; k0 < K; k0 += BKK) {
        const int cur = (k0 >> 6) & 1;
        if (k0 + BKK < K) {
            const int nxt = cur ^ 1;
#pragma unroll
            for (int t = 0; t < 4; ++t) {
                gl_lds16(gA + (size_t)t * 8 * K + k0 + BKK, &As[nxt][ldso + t * 8 * BKK]);
                gl_lds16(gW + (size_t)t * 8 * K + k0 + BKK, &Ws[nxt][ldso + t * 8 * BKK]);
            }
        }
#pragma unroll
        for (int kh = 0; kh < 2; ++kh) {
            bf16x8 af[4], bf[4];
            const int co = ((kh * 4 + quad) ^ swf) * 8;
#pragma unroll
            for (int i = 0; i < 4; ++i) {
                af[i] = *(const bf16x8*)&As[cur][(wr * 64 + i * 16 + fr) * BKK + co];
                bf[i] = *(const bf16x8*)&Ws[cur][(wc * 64 + i * 16 + fr) * BKK + co];
            }
#pragma unroll
            for (int i = 0; i < 4; ++i)
#pragma unroll
                for (int j = 0; j < 4; ++j)
                    acc[i][j] = __builtin_amdgcn_mfma_f32_16x16x32_bf16(af[i], bf[j], acc[i][j], 0, 0, 0);
        }
        __syncthreads();   // drains prefetch vmcnt + fragment lgkm; one barrier/K-step
    }

#pragma unroll
    for (int j = 0; j < 4; ++j) {
        int col = n0l + wc * 64 + j * 16 + fr;
        float bvl = bias[col];
#pragma unroll
        for (int i = 0; i < 4; ++i) {
#pragma unroll
            for (int r = 0; r < 4; ++r) {
                int row = m0 + wr * 64 + i * 16 + quad * 4 + r;
                ushort hv = f2bf(acc[i][j][r] + bvl);
                if (region == 0) {
                    Cq[(size_t)row * 1024 + col] = hv;
                } else if (region == 1) {
                    Ck[(size_t)row * 1024 + col] = hv;
                } else {
                    int bb = row >> 11, s = row & 2047;
                    int hh = col >> 6, d = col & 63;
                    CvT[(((size_t)bb * NH + hh) * HD + d) * SEQ + s] = hv;
                }
            }
        }
    }
}

// ---------------------------------------------------------------------------
// Output projection GEMM (+bias +fp32 residual), same BK=64 dbuf structure.
// ---------------------------------------------------------------------------
__global__ __launch_bounds__(256) void gemm_out(
    const ushort* __restrict__ A, const ushort* __restrict__ W,
    const float* __restrict__ bias, const float* __restrict__ resid,
    float* __restrict__ Cf, int M, int N, int K)
{
    __shared__ ushort As[2][BM * BKK];
    __shared__ ushort Ws[2][BM * BKK];
    const int tid = threadIdx.x;
    const int lane = tid & 63;
    const int wave = tid >> 6;
    const int wr = wave >> 1, wc = wave & 1;
    const int m0 = blockIdx.y * BM, n0 = blockIdx.x * BM;
    const int fr = lane & 15, quad = lane >> 4;
    const int r8 = lane >> 3, c8 = lane & 7;
    const int gc8 = c8 ^ r8;
    const int swf = fr & 7;

    const ushort* gA = A + (size_t)(m0 + wave * 32 + r8) * K + gc8 * 8;
    const ushort* gW = W + (size_t)(n0 + wave * 32 + r8) * K + gc8 * 8;
    const int ldso = (wave * 32) * BKK;

    f32x4 acc[4][4] = {};

    // prologue: stage tile 0 into buffer 0
#pragma unroll
    for (int t = 0; t < 4; ++t) {
        gl_lds16(gA + (size_t)t * 8 * K, &As[0][ldso + t * 8 * BKK]);
        gl_lds16(gW + (size_t)t * 8 * K, &Ws[0][ldso + t * 8 * BKK]);
    }
    __syncthreads();

    for (int k0 = 0; k0 < K; k0 += BKK) {
        const int cur = (k0 >> 6) & 1;
        if (k0 + BKK < K) {
            const int nxt = cur ^ 1;
#pragma unroll
            for (int t = 0; t < 4; ++t) {
                gl_lds16(gA + (size_t)t * 8 * K + k0 + BKK, &As[nxt][ldso + t * 8 * BKK]);
                gl_lds16(gW + (size_t)t * 8 * K + k0 + BKK, &Ws[nxt][ldso + t * 8 * BKK]);
            }
        }
#pragma unroll
        for (int kh = 0; kh < 2; ++kh) {
            bf16x8 af[4], bf[4];
            const int co = ((kh * 4 + quad) ^ swf) * 8;
#pragma unroll
            for (int i = 0; i < 4; ++i) {
                af[i] = *(const bf16x8*)&As[cur][(wr * 64 + i * 16 + fr) * BKK + co];
                bf[i] = *(const bf16x8*)&Ws[cur][(wc * 64 + i * 16 + fr) * BKK + co];
            }
#pragma unroll
            for (int i = 0; i < 4; ++i)
#pragma unroll
                for (int j = 0; j < 4; ++j)
                    acc[i][j] = __builtin_amdgcn_mfma_f32_16x16x32_bf16(af[i], bf[j], acc[i][j], 0, 0, 0);
        }
        __syncthreads();
    }

#pragma unroll
    for (int j = 0; j < 4; ++j) {
        int col = n0 + wc * 64 + j * 16 + fr;
        float bvl = bias[col];
#pragma unroll
        for (int i = 0; i < 4; ++i) {
#pragma unroll
            for (int r = 0; r < 4; ++r) {
                int row = m0 + wr * 64 + i * 16 + quad * 4 + r;
                Cf[(size_t)row * N + col] =
                    acc[i][j][r] + bvl + resid[(size_t)row * N + col];
            }
        }
    }
}

// ---------------------------------------------------------------------------
// MFMA flash attention, S^T formulation, 128 q-rows per block (2 strips per
// wave). K/V LDS double-buffered, one barrier per kb. Paired q-tiles
// (qt, 15-qt) per block: uniform 34 iters (grid split to 1024 regressed).
//  - XCD-aware 1D grid: 8 bx-blocks sharing one (b,h) K/V stream -> same XCD.
//  - raw v_exp_f32 inline asm; v_cvt_pk_bf16_f32 P-pack; setprio(1) on MFMA.
// ---------------------------------------------------------------------------
#define PSP 72
__global__ __launch_bounds__(256, 3) void flash_mfma(
    const ushort* __restrict__ Q, const ushort* __restrict__ K,
    const ushort* __restrict__ VtG, const float* __restrict__ mask,
    ushort* __restrict__ O)
{
    const int id = blockIdx.x;
    const int bx = id >> 6;          // q-tile pair selector 0..7
    const int hb = id & 63;          // xcd = hb % 8 under round-robin
    const int h = hb & 15, b = hb >> 4;
    __shared__ ushort Ks[2][64 * 64];    // [key][d], swizzled 16B chunks
    __shared__ ushort Vt[2][64 * 64];    // [d][key], swizzled 16B chunks
    __shared__ ushort Ps[128 * PSP];     // [q][key], wave-private strips
    const int tid = threadIdx.x;
    const int lane = tid & 63, wave = tid >> 6;
    const int fr = lane & 15, quad = lane >> 4;
    const int srow = tid >> 3;
    const int sc8 = tid & 7;
    const int g8 = sc8 ^ (srow & 7);
    const int swf = fr & 7;

    const ushort* gK0 = K + (size_t)(b * SEQ) * D + h * HD + (size_t)srow * D + g8 * 8;
    const ushort* gK1 = gK0 + (size_t)32 * D;
    const ushort* gV0 = VtG + ((size_t)(b * NH + h) * HD + srow) * SEQ + g8 * 8;
    const ushort* gV1 = gV0 + (size_t)32 * SEQ;
    const float* mrow = mask + (size_t)b * SEQ;
    const float SCALE2 = 0.125f * LOG2E;
    const float MASKC = -10000.0f * LOG2E;

    for (int phase = 0; phase < 2; ++phase) {
        const int qt = phase ? (15 - bx) : bx;      // 128-row q tile
        const int q0 = qt * 128;
        // Q B-fragments for both strips, straight from global
        bf16x8 qf[2][2];
#pragma unroll
        for (int s = 0; s < 2; ++s) {
            const ushort* qptr = Q + ((size_t)(b * SEQ + q0 + s * 64 + wave * 16 + fr)) * D
                                   + h * HD + quad * 8;
            qf[s][0] = *(const bf16x8*)(qptr);
            qf[s][1] = *(const bf16x8*)(qptr + 32);
        }

        f32x4 oacc[2][4] = {};
        float lsum[2][4] = {};
        const int nkb = 2 * qt + 2;

        // prologue: stage kb=0 into buffer 0
        gl_lds16(gK0, &Ks[0][wave * 512]);
        gl_lds16(gK1, &Ks[0][2048 + wave * 512]);
        gl_lds16(gV0, &Vt[0][wave * 512]);
        gl_lds16(gV1, &Vt[0][2048 + wave * 512]);
        __syncthreads();

        for (int kb = 0; kb < nkb; ++kb) {
            const int cur = kb & 1;
            if (kb + 1 < nkb) {
                const int nxt = cur ^ 1;
                gl_lds16(gK0 + (size_t)(kb + 1) * 64 * D, &Ks[nxt][wave * 512]);
                gl_lds16(gK1 + (size_t)(kb + 1) * 64 * D, &Ks[nxt][2048 + wave * 512]);
                gl_lds16(gV0 + (kb + 1) * 64, &Vt[nxt][wave * 512]);
                gl_lds16(gV1 + (kb + 1) * 64, &Vt[nxt][2048 + wave * 512]);
            }
            f32x4 mv[4];
#pragma unroll
            for (int jt = 0; jt < 4; ++jt)
                mv[jt] = ((const f32x4*)(mrow + kb * 64))[jt * 4 + quad];

            const bool s0act = (kb <= 2 * qt);      // strip0 active (wave-uniform)

            // ---- S^T = K·Q^T for both strips (K frags shared) ----
            f32x4 sacc[2][4] = {};
            __builtin_amdgcn_s_setprio(1);
#pragma unroll
            for (int jt = 0; jt < 4; ++jt) {
                const int rb = (jt * 16 + fr) * 64;
                bf16x8 kf0 = *(const bf16x8*)&Ks[cur][rb + ((quad) ^ swf) * 8];
                bf16x8 kf1 = *(const bf16x8*)&Ks[cur][rb + ((4 + quad) ^ swf) * 8];
                sacc[0][jt] = __builtin_amdgcn_mfma_f32_16x16x32_bf16(kf0, qf[0][0], sacc[0][jt], 0, 0, 0);
                sacc[0][jt] = __builtin_amdgcn_mfma_f32_16x16x32_bf16(kf1, qf[0][1], sacc[0][jt], 0, 0, 0);
                sacc[1][jt] = __builtin_amdgcn_mfma_f32_16x16x32_bf16(kf0, qf[1][0], sacc[1][jt], 0, 0, 0);
                sacc[1][jt] = __builtin_amdgcn_mfma_f32_16x16x32_bf16(kf1, qf[1][1], sacc[1][jt], 0, 0, 0);
            }
            __builtin_amdgcn_s_setprio(0);

            // ---- softmax (fixed-max, raw v_exp_f32, cvt_pk bf16 P) ----
            float padd[4][4];
#pragma unroll
            for (int jt = 0; jt < 4; ++jt)
#pragma unroll
                for (int r = 0; r < 4; ++r)
                    padd[jt][r] = fmaf(mv[jt][r], -MASKC, MASKC);
            const int ql = wave * 16 + fr;
#pragma unroll
            for (int s = 0; s < 2; ++s) {
                if (s == 0 && !s0act) continue;
                const bool diag = (kb == 2 * qt + s);
#pragma unroll
                for (int jt = 0; jt < 4; ++jt) {
                    float p[4];
#pragma unroll
                    for (int r = 0; r < 4; ++r) {
                        float v = fmaf(sacc[s][jt][r], SCALE2, padd[jt][r]);
                        if (diag) {
                            int keyl = jt * 16 + quad * 4 + r;
                            v = (keyl > ql) ? -1e30f : v;
                        }
                        float e = exp2_raw(v);
                        p[r] = e;
                        lsum[s][r] += e;
                    }
                    uint w0, w1;
                    asm("v_cvt_pk_bf16_f32 %0, %1, %2" : "=v"(w0) : "v"(p[0]), "v"(p[1]));
                    asm("v_cvt_pk_bf16_f32 %0, %1, %2" : "=v"(w1) : "v"(p[2]), "v"(p[3]));
                    union { uint2 u; ushort4 us; } pu;
                    pu.u.x = w0; pu.u.y = w1;
                    *(ushort4*)&Ps[(s * 64 + wave * 16 + fr) * PSP + jt * 16 + quad * 4] = pu.us;
                }
            }
            // Ps strips are wave-private: no barrier needed.

            // ---- O += P·V (V frags shared across strips) ----
            bf16x8 pa[2][2];
#pragma unroll
            for (int s = 0; s < 2; ++s) {
                pa[s][0] = *(const bf16x8*)&Ps[(s * 64 + wave * 16 + fr) * PSP + quad * 8];
                pa[s][1] = *(const bf16x8*)&Ps[(s * 64 + wave * 16 + fr) * PSP + 32 + quad * 8];
            }
            __builtin_amdgcn_s_setprio(1);
#pragma unroll
            for (int dt = 0; dt < 4; ++dt) {
                const int rb = (dt * 16 + fr) * 64;
                bf16x8 vf0 = *(const bf16x8*)&Vt[cur][rb + ((quad) ^ swf) * 8];
                bf16x8 vf1 = *(const bf16x8*)&Vt[cur][rb + ((4 + quad) ^ swf) * 8];
                if (s0act) {
                    oacc[0][dt] = __builtin_amdgcn_mfma_f32_16x16x32_bf16(pa[0][0], vf0, oacc[0][dt], 0, 0, 0);
                    oacc[0][dt] = __builtin_amdgcn_mfma_f32_16x16x32_bf16(pa[0][1], vf1, oacc[0][dt], 0, 0, 0);
                }
                oacc[1][dt] = __builtin_amdgcn_mfma_f32_16x16x32_bf16(pa[1][0], vf0, oacc[1][dt], 0, 0, 0);
                oacc[1][dt] = __builtin_amdgcn_mfma_f32_16x16x32_bf16(pa[1][1], vf1, oacc[1][dt], 0, 0, 0);
            }
            __builtin_amdgcn_s_setprio(0);
            __syncthreads();   // drains prefetch vmcnt + all LDS reads of buf[cur]
        }

        // ---- finalize both strips ----
#pragma unroll
        for (int s = 0; s < 2; ++s) {
            float lt = (lsum[s][0] + lsum[s][1]) + (lsum[s][2] + lsum[s][3]);
            lt += __shfl_xor(lt, 16, 64);
            lt += __shfl_xor(lt, 32, 64);
            float linv[4];
#pragma unroll
            for (int r = 0; r < 4; ++r)
                linv[r] = 1.0f / __shfl(lt, quad * 4 + r, 64);
#pragma unroll
            for (int dt = 0; dt < 4; ++dt)
#pragma unroll
                for (int r = 0; r < 4; ++r) {
                    int q = q0 + s * 64 + wave * 16 + quad * 4 + r;
                    O[((size_t)(b * SEQ + q)) * D + h * HD + dt * 16 + fr] =
                        f2bf(oacc[s][dt][r] * linv[r]);
                }
        }
    }
}

// ---------------------------------------------------------------------------
extern "C" void kernel_launch(void* const* d_in, const int* in_sizes, int n_in,
                              void* d_out, int out_size, void* d_ws, size_t ws_size,
                              hipStream_t stream)
{
    const float* x     = (const float*)d_in[0];
    const float* amask = (const float*)d_in[1];
    const float* Wq    = (const float*)d_in[2];
    const float* bq    = (const float*)d_in[3];
    const float* Wk    = (const float*)d_in[4];
    const float* bk    = (const float*)d_in[5];
    const float* Wv    = (const float*)d_in[6];
    const float* bv    = (const float*)d_in[7];
    const float* Wo    = (const float*)d_in[8];
    const float* bo    = (const float*)d_in[9];
    const float* gamma = (const float*)d_in[10];
    const float* beta  = (const float*)d_in[11];
    float* out = (float*)d_out;

    const size_t MROWS = (size_t)BATCH * SEQ;  // 8192
    const size_t MB = 1024 * 1024;
    char* ws = (char*)d_ws;
    ushort* Qb    = (ushort*)(ws);             // 16 MB bf16 [B,S,D]
    ushort* Kb    = (ushort*)(ws + 16 * MB);   // 16 MB [B,S,D]
    ushort* Vtb   = (ushort*)(ws + 32 * MB);   // 16 MB [B,H,D,S]
    ushort* xn_bf = (ushort*)(ws + 48 * MB);   // 16 MB (reused as attn_bf)
    ushort* Wq_bf = (ushort*)(ws + 64 * MB);   // Wq,Wk,Wv,Wo contiguous
    ushort* Wo_bf = (ushort*)(ws + 70 * MB);
    ushort* attn_bf = xn_bf;

    // fused LN (1 wave/row, 2048 blocks) + weight-convert (4096 blocks)
    prep<<<dim3((unsigned)(MROWS / 4 + 4096)), 256, 0, stream>>>(
        x, gamma, beta, xn_bf, Wq, Wk, Wv, Wo, Wq_bf);

    gemm_qkv<<<dim3(24, 64), 256, 0, stream>>>(xn_bf, Wq_bf, bq, bk, bv,
                                               Qb, Kb, Vtb, (int)MROWS, D);

    flash_mfma<<<dim3(512), 256, 0, stream>>>(Qb, Kb, Vtb, amask, attn_bf);

    gemm_out<<<dim3(8, 64), 256, 0, stream>>>(attn_bf, Wo_bf, bo, x, out,
                                              (int)MROWS, D, D);
}

// Round 11
// 269.995 us; speedup vs baseline: 1.0611x; 1.0111x over previous
//
#include <hip/hip_runtime.h>

#define D 1024
#define NH 16
#define HD 64
#define SEQ 2048
#define BATCH 4
#define LN_EPS 1e-5f
#define LOG2E 1.44269504088896f

typedef __attribute__((ext_vector_type(8))) __bf16 bf16x8;
typedef __attribute__((ext_vector_type(4))) float f32x4;

__device__ __forceinline__ ushort f2bf(float f) {
    union { float f; uint u; } c; c.f = f;
    uint u = c.u + 0x7fffu + ((c.u >> 16) & 1u);   // RNE
    return (ushort)(u >> 16);
}

// async global->LDS DMA, 16B per lane; LDS dest = wave-uniform base + lane*16
__device__ __forceinline__ void gl_lds16(const ushort* g, ushort* lds) {
    __builtin_amdgcn_global_load_lds(
        (const __attribute__((address_space(1))) void*)g,
        (__attribute__((address_space(3))) void*)lds, 16, 0, 0);
}

// raw v_exp_f32: D = 2^S0 (cdna4_isa §3). Single VALU inst, no OCML path.
__device__ __forceinline__ float exp2_raw(float v) {
    float e;
    asm("v_exp_f32 %0, %1" : "=v"(e) : "v"(v));
    return e;
}

// ---------------------------------------------------------------------------
// prep: fused {LayerNorm rows} + {fp32->bf16 convert of 4 weight matrices}.
// LN = one wave per row (4 rows/block), pure shfl_xor butterfly — zero
// barriers, zero LDS. (Round-10 verified: −6.4us vs 4-wave version.)
// ---------------------------------------------------------------------------
__global__ __launch_bounds__(256) void prep(
    const float* __restrict__ x, const float* __restrict__ gamma,
    const float* __restrict__ beta, ushort* __restrict__ xn,
    const float* __restrict__ w0, const float* __restrict__ w1,
    const float* __restrict__ w2, const float* __restrict__ w3,
    ushort* __restrict__ wout)
{
    const int bid = blockIdx.x;
    const int tid = threadIdx.x;
    if (bid < BATCH * SEQ / 4) {
        // ---- LayerNorm: one row per wave ----
        const int wave = tid >> 6, lane = tid & 63;
        const int row = bid * 4 + wave;
        const float4* xr = (const float4*)(x + (size_t)row * D);
        float4 v[4];
        float s = 0.f;
#pragma unroll
        for (int t = 0; t < 4; ++t) {
            v[t] = xr[t * 64 + lane];
            s += (v[t].x + v[t].y) + (v[t].z + v[t].w);
        }
#pragma unroll
        for (int off = 32; off > 0; off >>= 1) s += __shfl_xor(s, off, 64);
        float mean = s * (1.0f / D);
        float ss = 0.f;
#pragma unroll
        for (int t = 0; t < 4; ++t) {
            float dx = v[t].x - mean, dy = v[t].y - mean;
            float dz = v[t].z - mean, dw = v[t].w - mean;
            ss += (dx * dx + dy * dy) + (dz * dz + dw * dw);
        }
#pragma unroll
        for (int off = 32; off > 0; off >>= 1) ss += __shfl_xor(ss, off, 64);
        float rstd = rsqrtf(ss * (1.0f / D) + LN_EPS);
        ushort4* xo = (ushort4*)(xn + (size_t)row * D);
#pragma unroll
        for (int t = 0; t < 4; ++t) {
            float4 g = ((const float4*)gamma)[t * 64 + lane];
            float4 b = ((const float4*)beta)[t * 64 + lane];
            ushort4 o;
            o.x = f2bf((v[t].x - mean) * rstd * g.x + b.x);
            o.y = f2bf((v[t].y - mean) * rstd * g.y + b.y);
            o.z = f2bf((v[t].z - mean) * rstd * g.z + b.z);
            o.w = f2bf((v[t].w - mean) * rstd * g.w + b.w);
            xo[t * 64 + lane] = o;
        }
    } else {
        // ---- weight convert ----
        const int n = D * D;
        int p = bid - BATCH * SEQ / 4;
        int sel = p >> 10;                 // 0..3
        int xblk = p & 1023;
        const float* in = sel == 0 ? w0 : (sel == 1 ? w1 : (sel == 2 ? w2 : w3));
        int i = (xblk * 256 + tid) * 4;
        float4 v = *(const float4*)(in + i);
        ushort4 o;
        o.x = f2bf(v.x); o.y = f2bf(v.y); o.z = f2bf(v.z); o.w = f2bf(v.w);
        *(ushort4*)(wout + (size_t)sel * n + i) = o;
    }
}

// ---------------------------------------------------------------------------
// GEMM (final form): 128x128 tile, BK=64, XOR-swizzled DMA staging, 2-phase
// double-buffer with a single compiler-scheduled __syncthreads per K-step.
// SESSION VERDICT on alternatives (all measured, all regressed):
//   - 256^2 coarse 2-phase + counted vmcnt: 115.6us (1 blk/CU, 1.5-round
//     tail, V-scatter write burst 52->82MB).
//   - BK=32 (5 blk/CU theoretical): 94.7us (2x barrier count; real residency
//     scheduler-limited — Occupancy rose 16.5->26 but MfmaUtil FELL).
//   - counted vmcnt(8) + 2 raw barriers at 128^2: 94.7us (consistent with
//     catalog regime-gate: T4 counted-vmcnt is null/negative without the
//     full T3 8-phase interleave).
// This structure (89.5us, MfmaUtil 23.5) is the 2-phase ceiling for this
// shape; past it requires the full 8-phase ledger (not safely derivable here).
// ---------------------------------------------------------------------------
#define BM 128
#define BKK 64

// ---------------------------------------------------------------------------
// Fused QKV GEMM: W = stacked [Wq;Wk;Wv] = [3072][1024] bf16. Grid (24, 64).
// Region 0->Q, 1->K row-major bf16; region 2 -> V transposed to [B,H,D,S].
// ---------------------------------------------------------------------------
__global__ __launch_bounds__(256) void gemm_qkv(
    const ushort* __restrict__ A,    // [M,1024] bf16
    const ushort* __restrict__ W,    // [3072,1024] bf16
    const float* __restrict__ bq, const float* __restrict__ bk,
    const float* __restrict__ bv,
    ushort* __restrict__ Cq, ushort* __restrict__ Ck,
    ushort* __restrict__ CvT,
    int M, int K)
{
    __shared__ ushort As[2][BM * BKK];   // 2 x 16 KB
    __shared__ ushort Ws[2][BM * BKK];
    const int tid = threadIdx.x;
    const int lane = tid & 63;
    const int wave = tid >> 6;
    const int wr = wave >> 1, wc = wave & 1;
    const int m0 = blockIdx.y * BM;
    const int n0g = blockIdx.x * BM;
    const int region = n0g >> 10;
    const int n0l = n0g & 1023;
    const float* bias = region == 0 ? bq : (region == 1 ? bk : bv);
    const int fr = lane & 15, quad = lane >> 4;
    const int r8 = lane >> 3, c8 = lane & 7;
    const int gc8 = c8 ^ r8;               // swizzled global chunk
    const int swf = fr & 7;

    const ushort* gA = A + (size_t)(m0 + wave * 32 + r8) * K + gc8 * 8;
    const ushort* gW = W + (size_t)(n0g + wave * 32 + r8) * K + gc8 * 8;
    const int ldso = (wave * 32) * BKK;

    f32x4 acc[4][4] = {};

    // prologue: stage tile 0 into buffer 0
#pragma unroll
    for (int t = 0; t < 4; ++t) {
        gl_lds16(gA + (size_t)t * 8 * K, &As[0][ldso + t * 8 * BKK]);
        gl_lds16(gW + (size_t)t * 8 * K, &Ws[0][ldso + t * 8 * BKK]);
    }
    __syncthreads();

    for (int k0 = 0; k0 < K; k0 += BKK) {
        const int cur = (k0 >> 6) & 1;
        if (k0 + BKK < K) {
            const int nxt = cur ^ 1;
#pragma unroll
            for (int t = 0; t < 4; ++t) {
                gl_lds16(gA + (size_t)t * 8 * K + k0 + BKK, &As[nxt][ldso + t * 8 * BKK]);
                gl_lds16(gW + (size_t)t * 8 * K + k0 + BKK, &Ws[nxt][ldso + t * 8 * BKK]);
            }
        }
#pragma unroll
        for (int kh = 0; kh < 2; ++kh) {
            bf16x8 af[4], bf[4];
            const int co = ((kh * 4 + quad) ^ swf) * 8;
#pragma unroll
            for (int i = 0; i < 4; ++i) {
                af[i] = *(const bf16x8*)&As[cur][(wr * 64 + i * 16 + fr) * BKK + co];
                bf[i] = *(const bf16x8*)&Ws[cur][(wc * 64 + i * 16 + fr) * BKK + co];
            }
#pragma unroll
            for (int i = 0; i < 4; ++i)
#pragma unroll
                for (int j = 0; j < 4; ++j)
                    acc[i][j] = __builtin_amdgcn_mfma_f32_16x16x32_bf16(af[i], bf[j], acc[i][j], 0, 0, 0);
        }
        __syncthreads();   // drains prefetch vmcnt + fragment lgkm; one barrier/K-step
    }

#pragma unroll
    for (int j = 0; j < 4; ++j) {
        int col = n0l + wc * 64 + j * 16 + fr;
        float bvl = bias[col];
#pragma unroll
        for (int i = 0; i < 4; ++i) {
#pragma unroll
            for (int r = 0; r < 4; ++r) {
                int row = m0 + wr * 64 + i * 16 + quad * 4 + r;
                ushort hv = f2bf(acc[i][j][r] + bvl);
                if (region == 0) {
                    Cq[(size_t)row * 1024 + col] = hv;
                } else if (region == 1) {
                    Ck[(size_t)row * 1024 + col] = hv;
                } else {
                    int bb = row >> 11, s = row & 2047;
                    int hh = col >> 6, d = col & 63;
                    CvT[(((size_t)bb * NH + hh) * HD + d) * SEQ + s] = hv;
                }
            }
        }
    }
}

// ---------------------------------------------------------------------------
// Output projection GEMM (+bias +fp32 residual), same BK=64 dbuf structure.
// ---------------------------------------------------------------------------
__global__ __launch_bounds__(256) void gemm_out(
    const ushort* __restrict__ A, const ushort* __restrict__ W,
    const float* __restrict__ bias, const float* __restrict__ resid,
    float* __restrict__ Cf, int M, int N, int K)
{
    __shared__ ushort As[2][BM * BKK];
    __shared__ ushort Ws[2][BM * BKK];
    const int tid = threadIdx.x;
    const int lane = tid & 63;
    const int wave = tid >> 6;
    const int wr = wave >> 1, wc = wave & 1;
    const int m0 = blockIdx.y * BM, n0 = blockIdx.x * BM;
    const int fr = lane & 15, quad = lane >> 4;
    const int r8 = lane >> 3, c8 = lane & 7;
    const int gc8 = c8 ^ r8;
    const int swf = fr & 7;

    const ushort* gA = A + (size_t)(m0 + wave * 32 + r8) * K + gc8 * 8;
    const ushort* gW = W + (size_t)(n0 + wave * 32 + r8) * K + gc8 * 8;
    const int ldso = (wave * 32) * BKK;

    f32x4 acc[4][4] = {};

    // prologue: stage tile 0 into buffer 0
#pragma unroll
    for (int t = 0; t < 4; ++t) {
        gl_lds16(gA + (size_t)t * 8 * K, &As[0][ldso + t * 8 * BKK]);
        gl_lds16(gW + (size_t)t * 8 * K, &Ws[0][ldso + t * 8 * BKK]);
    }
    __syncthreads();

    for (int k0 = 0; k0 < K; k0 += BKK) {
        const int cur = (k0 >> 6) & 1;
        if (k0 + BKK < K) {
            const int nxt = cur ^ 1;
#pragma unroll
            for (int t = 0; t < 4; ++t) {
                gl_lds16(gA + (size_t)t * 8 * K + k0 + BKK, &As[nxt][ldso + t * 8 * BKK]);
                gl_lds16(gW + (size_t)t * 8 * K + k0 + BKK, &Ws[nxt][ldso + t * 8 * BKK]);
            }
        }
#pragma unroll
        for (int kh = 0; kh < 2; ++kh) {
            bf16x8 af[4], bf[4];
            const int co = ((kh * 4 + quad) ^ swf) * 8;
#pragma unroll
            for (int i = 0; i < 4; ++i) {
                af[i] = *(const bf16x8*)&As[cur][(wr * 64 + i * 16 + fr) * BKK + co];
                bf[i] = *(const bf16x8*)&Ws[cur][(wc * 64 + i * 16 + fr) * BKK + co];
            }
#pragma unroll
            for (int i = 0; i < 4; ++i)
#pragma unroll
                for (int j = 0; j < 4; ++j)
                    acc[i][j] = __builtin_amdgcn_mfma_f32_16x16x32_bf16(af[i], bf[j], acc[i][j], 0, 0, 0);
        }
        __syncthreads();
    }

#pragma unroll
    for (int j = 0; j < 4; ++j) {
        int col = n0 + wc * 64 + j * 16 + fr;
        float bvl = bias[col];
#pragma unroll
        for (int i = 0; i < 4; ++i) {
#pragma unroll
            for (int r = 0; r < 4; ++r) {
                int row = m0 + wr * 64 + i * 16 + quad * 4 + r;
                Cf[(size_t)row * N + col] =
                    acc[i][j][r] + bvl + resid[(size_t)row * N + col];
            }
        }
    }
}

// ---------------------------------------------------------------------------
// MFMA flash attention, S^T formulation, 128 q-rows per block (2 strips per
// wave). K/V LDS double-buffered, one barrier per kb. Paired q-tiles
// (qt, 15-qt) per block: uniform 34 iters (grid split to 1024 regressed).
//  - XCD-aware 1D grid: 8 bx-blocks sharing one (b,h) K/V stream -> same XCD.
//  - raw v_exp_f32 inline asm; v_cvt_pk_bf16_f32 P-pack; setprio(1) on MFMA.
// Round 11: phase-boundary prefetch — on phase 0's LAST iteration, restage
// kb=0 K/V (same pointers both phases) into buf[0] (free: nkb even -> last
// cur=1). The end-of-iter __syncthreads (vmcnt(0) drain) publishes it, so
// phase 1 skips its serial prologue staging + barrier entirely.
// ---------------------------------------------------------------------------
#define PSP 72
__global__ __launch_bounds__(256, 3) void flash_mfma(
    const ushort* __restrict__ Q, const ushort* __restrict__ K,
    const ushort* __restrict__ VtG, const float* __restrict__ mask,
    ushort* __restrict__ O)
{
    const int id = blockIdx.x;
    const int bx = id >> 6;          // q-tile pair selector 0..7
    const int hb = id & 63;          // xcd = hb % 8 under round-robin
    const int h = hb & 15, b = hb >> 4;
    __shared__ ushort Ks[2][64 * 64];    // [key][d], swizzled 16B chunks
    __shared__ ushort Vt[2][64 * 64];    // [d][key], swizzled 16B chunks
    __shared__ ushort Ps[128 * PSP];     // [q][key], wave-private strips
    const int tid = threadIdx.x;
    const int lane = tid & 63, wave = tid >> 6;
    const int fr = lane & 15, quad = lane >> 4;
    const int srow = tid >> 3;
    const int sc8 = tid & 7;
    const int g8 = sc8 ^ (srow & 7);
    const int swf = fr & 7;

    const ushort* gK0 = K + (size_t)(b * SEQ) * D + h * HD + (size_t)srow * D + g8 * 8;
    const ushort* gK1 = gK0 + (size_t)32 * D;
    const ushort* gV0 = VtG + ((size_t)(b * NH + h) * HD + srow) * SEQ + g8 * 8;
    const ushort* gV1 = gV0 + (size_t)32 * SEQ;
    const float* mrow = mask + (size_t)b * SEQ;
    const float SCALE2 = 0.125f * LOG2E;
    const float MASKC = -10000.0f * LOG2E;

    for (int phase = 0; phase < 2; ++phase) {
        const int qt = phase ? (15 - bx) : bx;      // 128-row q tile
        const int q0 = qt * 128;
        // Q B-fragments for both strips, straight from global
        bf16x8 qf[2][2];
#pragma unroll
        for (int s = 0; s < 2; ++s) {
            const ushort* qptr = Q + ((size_t)(b * SEQ + q0 + s * 64 + wave * 16 + fr)) * D
                                   + h * HD + quad * 8;
            qf[s][0] = *(const bf16x8*)(qptr);
            qf[s][1] = *(const bf16x8*)(qptr + 32);
        }

        f32x4 oacc[2][4] = {};
        float lsum[2][4] = {};
        const int nkb = 2 * qt + 2;

        // prologue staging only at block start; phase 1's kb=0 buffer was
        // prefetched during phase 0's last iteration (published by its
        // end-of-iter __syncthreads).
        if (phase == 0) {
            gl_lds16(gK0, &Ks[0][wave * 512]);
            gl_lds16(gK1, &Ks[0][2048 + wave * 512]);
            gl_lds16(gV0, &Vt[0][wave * 512]);
            gl_lds16(gV1, &Vt[0][2048 + wave * 512]);
            __syncthreads();
        }

        for (int kb = 0; kb < nkb; ++kb) {
            const int cur = kb & 1;
            const bool last = (kb + 1 == nkb);
            if (!last || phase == 0) {
                // normal prefetch of kb+1; on phase 0's last iter, restage
                // kb=0 for phase 1 (nxt = nkb&1 = 0 since nkb even).
                const int nxt = cur ^ 1;
                const int kbn = last ? 0 : kb + 1;
                gl_lds16(gK0 + (size_t)kbn * 64 * D, &Ks[nxt][wave * 512]);
                gl_lds16(gK1 + (size_t)kbn * 64 * D, &Ks[nxt][2048 + wave * 512]);
                gl_lds16(gV0 + kbn * 64, &Vt[nxt][wave * 512]);
                gl_lds16(gV1 + kbn * 64, &Vt[nxt][2048 + wave * 512]);
            }
            f32x4 mv[4];
#pragma unroll
            for (int jt = 0; jt < 4; ++jt)
                mv[jt] = ((const f32x4*)(mrow + kb * 64))[jt * 4 + quad];

            const bool s0act = (kb <= 2 * qt);      // strip0 active (wave-uniform)

            // ---- S^T = K·Q^T for both strips (K frags shared) ----
            f32x4 sacc[2][4] = {};
            __builtin_amdgcn_s_setprio(1);
#pragma unroll
            for (int jt = 0; jt < 4; ++jt) {
                const int rb = (jt * 16 + fr) * 64;
                bf16x8 kf0 = *(const bf16x8*)&Ks[cur][rb + ((quad) ^ swf) * 8];
                bf16x8 kf1 = *(const bf16x8*)&Ks[cur][rb + ((4 + quad) ^ swf) * 8];
                sacc[0][jt] = __builtin_amdgcn_mfma_f32_16x16x32_bf16(kf0, qf[0][0], sacc[0][jt], 0, 0, 0);
                sacc[0][jt] = __builtin_amdgcn_mfma_f32_16x16x32_bf16(kf1, qf[0][1], sacc[0][jt], 0, 0, 0);
                sacc[1][jt] = __builtin_amdgcn_mfma_f32_16x16x32_bf16(kf0, qf[1][0], sacc[1][jt], 0, 0, 0);
                sacc[1][jt] = __builtin_amdgcn_mfma_f32_16x16x32_bf16(kf1, qf[1][1], sacc[1][jt], 0, 0, 0);
            }
            __builtin_amdgcn_s_setprio(0);

            // ---- softmax (fixed-max, raw v_exp_f32, cvt_pk bf16 P) ----
            float padd[4][4];
#pragma unroll
            for (int jt = 0; jt < 4; ++jt)
#pragma unroll
                for (int r = 0; r < 4; ++r)
                    padd[jt][r] = fmaf(mv[jt][r], -MASKC, MASKC);
            const int ql = wave * 16 + fr;
#pragma unroll
            for (int s = 0; s < 2; ++s) {
                if (s == 0 && !s0act) continue;
                const bool diag = (kb == 2 * qt + s);
#pragma unroll
                for (int jt = 0; jt < 4; ++jt) {
                    float p[4];
#pragma unroll
                    for (int r = 0; r < 4; ++r) {
                        float v = fmaf(sacc[s][jt][r], SCALE2, padd[jt][r]);
                        if (diag) {
                            int keyl = jt * 16 + quad * 4 + r;
                            v = (keyl > ql) ? -1e30f : v;
                        }
                        float e = exp2_raw(v);
                        p[r] = e;
                        lsum[s][r] += e;
                    }
                    uint w0, w1;
                    asm("v_cvt_pk_bf16_f32 %0, %1, %2" : "=v"(w0) : "v"(p[0]), "v"(p[1]));
                    asm("v_cvt_pk_bf16_f32 %0, %1, %2" : "=v"(w1) : "v"(p[2]), "v"(p[3]));
                    union { uint2 u; ushort4 us; } pu;
                    pu.u.x = w0; pu.u.y = w1;
                    *(ushort4*)&Ps[(s * 64 + wave * 16 + fr) * PSP + jt * 16 + quad * 4] = pu.us;
                }
            }
            // Ps strips are wave-private: no barrier needed.

            // ---- O += P·V (V frags shared across strips) ----
            bf16x8 pa[2][2];
#pragma unroll
            for (int s = 0; s < 2; ++s) {
                pa[s][0] = *(const bf16x8*)&Ps[(s * 64 + wave * 16 + fr) * PSP + quad * 8];
                pa[s][1] = *(const bf16x8*)&Ps[(s * 64 + wave * 16 + fr) * PSP + 32 + quad * 8];
            }
            __builtin_amdgcn_s_setprio(1);
#pragma unroll
            for (int dt = 0; dt < 4; ++dt) {
                const int rb = (dt * 16 + fr) * 64;
                bf16x8 vf0 = *(const bf16x8*)&Vt[cur][rb + ((quad) ^ swf) * 8];
                bf16x8 vf1 = *(const bf16x8*)&Vt[cur][rb + ((4 + quad) ^ swf) * 8];
                if (s0act) {
                    oacc[0][dt] = __builtin_amdgcn_mfma_f32_16x16x32_bf16(pa[0][0], vf0, oacc[0][dt], 0, 0, 0);
                    oacc[0][dt] = __builtin_amdgcn_mfma_f32_16x16x32_bf16(pa[0][1], vf1, oacc[0][dt], 0, 0, 0);
                }
                oacc[1][dt] = __builtin_amdgcn_mfma_f32_16x16x32_bf16(pa[1][0], vf0, oacc[1][dt], 0, 0, 0);
                oacc[1][dt] = __builtin_amdgcn_mfma_f32_16x16x32_bf16(pa[1][1], vf1, oacc[1][dt], 0, 0, 0);
            }
            __builtin_amdgcn_s_setprio(0);
            __syncthreads();   // drains prefetch vmcnt + all LDS reads of buf[cur]
        }

        // ---- finalize both strips ----
#pragma unroll
        for (int s = 0; s < 2; ++s) {
            float lt = (lsum[s][0] + lsum[s][1]) + (lsum[s][2] + lsum[s][3]);
            lt += __shfl_xor(lt, 16, 64);
            lt += __shfl_xor(lt, 32, 64);
            float linv[4];
#pragma unroll
            for (int r = 0; r < 4; ++r)
                linv[r] = 1.0f / __shfl(lt, quad * 4 + r, 64);
#pragma unroll
            for (int dt = 0; dt < 4; ++dt)
#pragma unroll
                for (int r = 0; r < 4; ++r) {
                    int q = q0 + s * 64 + wave * 16 + quad * 4 + r;
                    O[((size_t)(b * SEQ + q)) * D + h * HD + dt * 16 + fr] =
                        f2bf(oacc[s][dt][r] * linv[r]);
                }
        }
    }
}

// ---------------------------------------------------------------------------
extern "C" void kernel_launch(void* const* d_in, const int* in_sizes, int n_in,
                              void* d_out, int out_size, void* d_ws, size_t ws_size,
                              hipStream_t stream)
{
    const float* x     = (const float*)d_in[0];
    const float* amask = (const float*)d_in[1];
    const float* Wq    = (const float*)d_in[2];
    const float* bq    = (const float*)d_in[3];
    const float* Wk    = (const float*)d_in[4];
    const float* bk    = (const float*)d_in[5];
    const float* Wv    = (const float*)d_in[6];
    const float* bv    = (const float*)d_in[7];
    const float* Wo    = (const float*)d_in[8];
    const float* bo    = (const float*)d_in[9];
    const float* gamma = (const float*)d_in[10];
    const float* beta  = (const float*)d_in[11];
    float* out = (float*)d_out;

    const size_t MROWS = (size_t)BATCH * SEQ;  // 8192
    const size_t MB = 1024 * 1024;
    char* ws = (char*)d_ws;
    ushort* Qb    = (ushort*)(ws);             // 16 MB bf16 [B,S,D]
    ushort* Kb    = (ushort*)(ws + 16 * MB);   // 16 MB [B,S,D]
    ushort* Vtb   = (ushort*)(ws + 32 * MB);   // 16 MB [B,H,D,S]
    ushort* xn_bf = (ushort*)(ws + 48 * MB);   // 16 MB (reused as attn_bf)
    ushort* Wq_bf = (ushort*)(ws + 64 * MB);   // Wq,Wk,Wv,Wo contiguous
    ushort* Wo_bf = (ushort*)(ws + 70 * MB);
    ushort* attn_bf = xn_bf;

    // fused LN (1 wave/row, 2048 blocks) + weight-convert (4096 blocks)
    prep<<<dim3((unsigned)(MROWS / 4 + 4096)), 256, 0, stream>>>(
        x, gamma, beta, xn_bf, Wq, Wk, Wv, Wo, Wq_bf);

    gemm_qkv<<<dim3(24, 64), 256, 0, stream>>>(xn_bf, Wq_bf, bq, bk, bv,
                                               Qb, Kb, Vtb, (int)MROWS, D);

    flash_mfma<<<dim3(512), 256, 0, stream>>>(Qb, Kb, Vtb, amask, attn_bf);

    gemm_out<<<dim3(8, 64), 256, 0, stream>>>(attn_bf, Wo_bf, bo, x, out,
                                              (int)MROWS, D, D);
}